// Round 7
// baseline (627.244 us; speedup 1.0000x reference)
//
#include <hip/hip_runtime.h>
#include <hip/hip_bf16.h>

#define N_SAMP    32768
#define NBINS     16384
#define NSIG      16
#define NBANDS    7
#define K_TOP     128
// padded per-signal band buffer: 64 zero-floats of guard before each band
// band i: size s=512<<i, payload offset poff(i) = 64*(i+1) + 512*((1<<i)-1)
#define BAND_STRIDE 65472   // 448 pad + 65024 payload

// staged bf16 layout: [x 16x32768 | filters 4096 | PT 8192 | PF 8192]
#define ST_X   0
#define ST_F   524288
#define ST_PT  528384
#define ST_PF  536576
#define ST_TOT 544864

#define TWO_PI 6.283185307179586f

__device__ __forceinline__ float bf2f(__hip_bfloat16 v) { return __bfloat162float(v); }

// order-preserving float->uint encoding (monotone)
__device__ __forceinline__ unsigned encf(float f) {
    unsigned u = __float_as_uint(f);
    return (u & 0x80000000u) ? ~u : (u | 0x80000000u);
}
__device__ __forceinline__ float decf(unsigned u) {
    return __uint_as_float((u & 0x80000000u) ? (u ^ 0x80000000u) : ~u);
}

// per-band two-step split constants: M = cnt = (b==0?256:s/4) = M1*M2, L = s/M1
__device__ __forceinline__ int band_M1sh(int b) { return b < 3 ? 4 : (b < 4 ? 5 : 6); }
__device__ __forceinline__ int band_Lsh(int b) {
    return b == 0 ? 5 : (b == 1 ? 6 : (b < 5 ? 7 : (b == 5 ? 8 : 9)));
}
__device__ __forceinline__ int band_M2(int b) {
    return b < 2 ? 16 : (b < 5 ? 32 : (b == 5 ? 64 : 128));
}

// ---------------------------------------------------------------------------
// K_stage: detect dtype per-block (no cross-block dep) + canonicalize inputs
// to bf16 staging; last block zeroes band guards + accum.
__global__ __launch_bounds__(256) void k_stage(
    const void* __restrict__ t, const void* __restrict__ r,
    const void* __restrict__ f, const void* __restrict__ pt,
    const void* __restrict__ pf,
    __hip_bfloat16* __restrict__ staged,
    float* __restrict__ bands, float* __restrict__ accum)
{
    const int tid = threadIdx.x;
    const int bx  = blockIdx.x;
    if (bx == (ST_TOT + 255) / 256) {          // tail block: guards + accum
        for (int i = tid; i < NSIG * 448; i += 256) {
            int sig = i / 448, rem = i - sig * 448;
            int g = rem >> 6, j = rem & 63;
            int off = 64 * g + 512 * ((1 << g) - 1);
            bands[(size_t)sig * BAND_STRIDE + off + j] = 0.f;
        }
        if (tid == 0) accum[0] = 0.f;
        return;
    }
    // local dtype detect from first 64 raw elements of target
    float pv = bf2f(((const __hip_bfloat16*)t)[tid & 63]);
    int bad = (fabsf(pv) > 1e8f) || (pv != pv);
    unsigned long long m = __ballot(bad);
    const int isf32 = (m != 0ull);
    const int id = bx * 256 + tid;
    if (id >= ST_TOT) return;
    const void* src; int idx;
    if (id < 262144)      { src = t;  idx = id; }
    else if (id < ST_F)   { src = r;  idx = id - 262144; }
    else if (id < ST_PT)  { src = f;  idx = id - ST_F; }
    else if (id < ST_PF)  { src = pt; idx = id - ST_PT; }
    else                  { src = pf; idx = id - ST_PF; }
    float v = isf32 ? ((const float*)src)[idx]
                    : bf2f(((const __hip_bfloat16*)src)[idx]);
    staged[id] = __float2bfloat16(v);
}

// ---------------------------------------------------------------------------
// Forward rfft via four-step: N = 128 x 256 (proven r5)
__global__ __launch_bounds__(256) void k_fwd1(
    const __hip_bfloat16* __restrict__ xstage, float* __restrict__ T)
{
    const int n2  = threadIdx.x;
    const int sig = blockIdx.y;
    const int k1b = blockIdx.x * 16;          // 16 k1 per block
    const __hip_bfloat16* x = xstage + (size_t)sig * N_SAMP;
    __shared__ float ct[128], st[128];
    if (n2 < 128) {
        float sv, cv;
        sincosf(TWO_PI * (float)n2 * (1.f / 128.f), &sv, &cv);
        ct[n2] = cv; st[n2] = sv;
    }
    __syncthreads();
    float ar[16], ai[16];
    #pragma unroll
    for (int q = 0; q < 16; ++q) { ar[q] = 0.f; ai[q] = 0.f; }
    for (int n1 = 0; n1 < 128; ++n1) {
        float xv = bf2f(x[n1 * 256 + n2]);
        #pragma unroll
        for (int q = 0; q < 16; ++q) {
            int t = (n1 * (k1b + q)) & 127;   // W128^{n1 k1} = (ct, -st)
            ar[q] = fmaf(xv,  ct[t], ar[q]);
            ai[q] = fmaf(xv, -st[t], ai[q]);
        }
    }
    float2* To = (float2*)T + (size_t)sig * 128 * 256;
    #pragma unroll
    for (int q = 0; q < 16; ++q) {
        int k1 = k1b + q;
        float sv, cv;                          // e^{-i th} = (cv, -sv)
        sincosf((TWO_PI / 32768.f) * (float)(n2 * k1), &sv, &cv);
        float Tr = ar[q] * cv + ai[q] * sv;
        float Ti = ai[q] * cv - ar[q] * sv;
        To[(size_t)k1 * 256 + n2] = make_float2(Tr, Ti);
    }
}

__global__ __launch_bounds__(128) void k_fwd2(
    const float* __restrict__ T, float* __restrict__ C)
{
    const int k2  = threadIdx.x;              // < 128
    const int k1  = blockIdx.x;
    const int sig = blockIdx.y;
    __shared__ float2 Ts[256];
    const float2* Tin = (const float2*)T + ((size_t)sig * 128 + k1) * 256;
    for (int i = k2; i < 256; i += 128) Ts[i] = Tin[i];
    __syncthreads();
    float sp, cp;
    sincosf(TWO_PI * (float)k2 * (1.f / 256.f), &sp, &cp);  // step = (cp,-sp)
    float er = 1.f, ei = 0.f, Xr = 0.f, Xi = 0.f;
    for (int n2 = 0; n2 < 256; ++n2) {
        float2 t = Ts[n2];
        Xr = fmaf(t.x, er, Xr); Xr = fmaf(-t.y, ei, Xr);
        Xi = fmaf(t.x, ei, Xi); Xi = fmaf( t.y, er, Xi);
        float nr = er * cp + ei * sp;
        ei       = ei * cp - er * sp;
        er = nr;
    }
    const float inv = 5.5242717280199030e-3f;   // 1/sqrt(32768)
    float2* Co = (float2*)C + (size_t)sig * NBINS;
    Co[k1 + 128 * k2] = make_float2(Xr * inv, Xi * inv);
}

// ---------------------------------------------------------------------------
// Band synthesis two-step (proven r5)
__global__ __launch_bounds__(256) void k_synthA(
    const float* __restrict__ C, float* __restrict__ G)
{
    const int tid = threadIdx.x;
    const int sig = blockIdx.y;
    int r = blockIdx.x;                 // band b owns (2<<b) blocks
    int band = 0;
    while (r >= (2 << band)) { r -= (2 << band); ++band; }
    const int s    = 512 << band;
    const int idx  = r * 256 + tid;
    const int m1sh = band_M1sh(band);
    const int lsh  = band_Lsh(band);
    const int M2   = band_M2(band);
    const int L    = 1 << lsh;
    const int a    = (band == 0) ? 0 : (128 << band);
    const int j1   = idx >> lsh;
    const int m    = idx & (L - 1);
    const float2* D = (const float2*)C + (size_t)sig * NBINS + a;
    float sv, cv;                       // rotation step e^{+2pi i m/L}
    sincosf(TWO_PI * (float)m / (float)L, &sv, &cv);
    float er = 1.f, ei = 0.f, gr = 0.f, gi = 0.f;
    for (int j2 = 0; j2 < M2; ++j2) {
        float2 d = D[j1 + (j2 << m1sh)];
        gr += d.x * er - d.y * ei;
        gi += d.x * ei + d.y * er;
        float nr = er * cv - ei * sv;
        ei       = er * sv + ei * cv;
        er = nr;
    }
    const float sc = 2.f * rsqrtf((float)s);
    float2* Go = (float2*)G + (size_t)sig * 65024 + 512 * ((1 << band) - 1);
    Go[idx] = make_float2(gr * sc, gi * sc);
}

__global__ __launch_bounds__(256) void k_synthB(
    const float* __restrict__ C, const float* __restrict__ G,
    float* __restrict__ bands)
{
    const int tid = threadIdx.x;
    const int sig = blockIdx.y;
    int r = blockIdx.x;
    int band = 0;
    while (r >= (2 << band)) { r -= (2 << band); ++band; }
    const int s    = 512 << band;
    const int n    = r * 256 + tid;
    const int M1   = 1 << band_M1sh(band);
    const int lsh  = band_Lsh(band);
    const int m    = n & ((1 << lsh) - 1);
    const float2* Gi = (const float2*)G + (size_t)sig * 65024 + 512 * ((1 << band) - 1);
    float sv, cv;                       // rotation step e^{+2pi i n/s}
    sincosf(TWO_PI * (float)n / (float)s, &sv, &cv);
    float er = 1.f, ei = 0.f, zr = 0.f, zi = 0.f;
    for (int j1 = 0; j1 < M1; ++j1) {
        float2 g = Gi[(j1 << lsh) + m];
        zr += g.x * er - g.y * ei;
        zi += g.x * ei + g.y * er;
        float nr = er * cv - ei * sv;
        ei       = er * sv + ei * cv;
        er = nr;
    }
    float val;
    if (band == 0) {
        val = zr - C[(size_t)sig * NBINS * 2] * 0.04419417382415922f; // 1/sqrt(512)
    } else {
        switch (n & 3) {                // Re(i^n * z)
            case 0:  val =  zr; break;
            case 1:  val = -zi; break;
            case 2:  val = -zr; break;
            default: val =  zi; break;
        }
    }
    const int poff = 64 * (band + 1) + 512 * ((1 << band) - 1);
    bands[(size_t)sig * BAND_STRIDE + poff + n] = val;
}

// ---------------------------------------------------------------------------
// K3: conv+segment-max, UNIFORM CHUNKS x 8 filters per block.
// 18 chunk slots cover all bands (4096-sample chunks; segments of width
// W=4<<band never straddle chunks). Window rw[80] loaded once, reused for
// 8 filters. Unique-writer plain stores to global segG[sig][band][f][128].
__global__ __launch_bounds__(256) void k_conv(
    const float* __restrict__ bands,
    const __hip_bfloat16* __restrict__ filters,
    float* __restrict__ segG)
{
    static const int sb[18] = {0,1,2,3,4,4,5,5,5,5,6,6,6,6,6,6,6,6};
    static const int sc[18] = {0,0,0,0,0,1,0,1,2,3,0,1,2,3,4,5,6,7};
    const int tid  = threadIdx.x;
    const int fg   = blockIdx.x & 7;
    const int slot = blockIdx.x >> 3;
    const int sig  = blockIdx.y;
    const int band = sb[slot];
    const int c0   = sc[slot] << 12;
    const int s    = 512 << band;
    const int poff = 64 * (band + 1) + 512 * ((1 << band) - 1);
    const float* bp = bands + (size_t)sig * BAND_STRIDE + poff;
    const int fbase = fg * 8;
    __shared__ float filt[512];
    for (int i = tid; i < 512; i += 256)
        filt[i] = bf2f(filters[(fbase + (i >> 6)) * 64 + (i & 63)]);
    __syncthreads();
    const int L = min(4096, s);
    if (16 * tid >= L) return;
    const int w0 = c0 + 16 * tid;
    float rw[80];                       // x[w0-64 .. w0+15]
    #pragma unroll
    for (int u = 0; u < 20; ++u) {
        float4 q = *reinterpret_cast<const float4*>(bp + (w0 - 64 + 4 * u));
        rw[4 * u + 0] = q.x; rw[4 * u + 1] = q.y;
        rw[4 * u + 2] = q.z; rw[4 * u + 3] = q.w;
    }
    float* segO = segG + ((size_t)(sig * NBANDS + band) * 64 + fbase) * 128;
    const int shift = 2 + band;
    for (int ff = 0; ff < 8; ++ff) {
        const float* fp = filt + ff * 64;
        float v[16];
        #pragma unroll
        for (int d = 0; d < 16; ++d) v[d] = 0.f;
        #pragma unroll
        for (int j = 0; j < 64; ++j) {
            float fj = fp[j];
            #pragma unroll
            for (int d = 0; d < 16; ++d)
                v[d] = fmaf(fj, rw[64 + d - j], v[d]);
        }
        float* so = segO + ff * 128;
        if (band == 0) {                // 4 whole segments of 4
            #pragma unroll
            for (int q = 0; q < 4; ++q)
                so[(w0 >> 2) + q] =
                    fmaxf(fmaxf(v[4*q], v[4*q+1]), fmaxf(v[4*q+2], v[4*q+3]));
        } else if (band == 1) {         // 2 whole segments of 8
            #pragma unroll
            for (int q = 0; q < 2; ++q) {
                float m = v[8*q];
                #pragma unroll
                for (int d = 1; d < 8; ++d) m = fmaxf(m, v[8*q + d]);
                so[(w0 >> 3) + q] = m;
            }
        } else {                        // one segment; g sharers in-wave
            float m = v[0];
            #pragma unroll
            for (int d = 1; d < 16; ++d) m = fmaxf(m, v[d]);
            const int g = 1 << (band - 2);      // 1..16 lanes per segment
            for (int off = 1; off < g; off <<= 1)
                m = fmaxf(m, __shfl_xor(m, off));
            if ((tid & (g - 1)) == 0)
                so[w0 >> shift] = m;
        }
    }
}

// ---------------------------------------------------------------------------
// K4: pool (from segG) + stable top-128 of 4096 per (sig,band)
__global__ __launch_bounds__(256) void k_topk(
    const float* __restrict__ segG,
    float* __restrict__ topv, int* __restrict__ topi)
{
    __shared__ unsigned long long keys[4096];
    const int tid = threadIdx.x;
    const int band = blockIdx.x, sig = blockIdx.y;
    const float* segB = segG + (size_t)(sig * NBANDS + band) * 64 * 128;
    for (int i = tid; i < 4096; i += 256) {
        int f = i >> 6, t = i & 63;
        const float* sg = segB + f * 128;
        float m = fmaxf(sg[2 * t], sg[2 * t + 1]);
        if (t > 0)  m = fmaxf(m, sg[2 * t - 1]);
        if (t < 63) m = fmaxf(m, sg[2 * t + 2]);
        keys[i] = ((unsigned long long)encf(m) << 32) | (unsigned)(4095 - i);
    }
    for (int k = 2; k <= 4096; k <<= 1) {
        for (int j = k >> 1; j > 0; j >>= 1) {
            __syncthreads();
            for (int i = tid; i < 4096; i += 256) {
                int l = i ^ j;
                if (l > i) {
                    unsigned long long av = keys[i], bv = keys[l];
                    bool up = ((i & k) == 0);
                    if ((av > bv) == up) { keys[i] = bv; keys[l] = av; }
                }
            }
        }
    }
    __syncthreads();
    if (tid < K_TOP) {
        unsigned long long key = keys[4095 - tid];
        const size_t ob = ((size_t)sig * NBANDS + band) * K_TOP + tid;
        topv[ob] = decf((unsigned)(key >> 32));
        topi[ob] = 4095 - (int)(key & 0xFFFFFFFFu);
    }
}

// ---------------------------------------------------------------------------
// K5: loss partial sums (proven r4)
__global__ __launch_bounds__(256) void k_loss(
    const float* __restrict__ topv, const int* __restrict__ topi,
    const __hip_bfloat16* __restrict__ PT, const __hip_bfloat16* __restrict__ PF,
    float* __restrict__ accum)
{
    const int tid = threadIdx.x;
    const int band = blockIdx.x, b = blockIdx.y;
    const size_t bt = ((size_t)b * NBANDS + band) * K_TOP;
    const size_t br = ((size_t)(8 + b) * NBANDS + band) * K_TOP;
    float sum = 0.f;
    for (int k = 0; k < K_TOP; ++k) {
        float vt = topv[bt + k]; int it = topi[bt + k];
        float vr = topv[br + k]; int ir = topi[br + k];
        if (tid < 128) {
            float a = vt * bf2f(PT[(it & 63) * 128 + tid]);
            float c = vr * bf2f(PT[(ir & 63) * 128 + tid]);
            sum += fabsf(a - c);
        } else {
            int j = tid - 128;
            float a = bf2f(PF[(it >> 6) * 128 + j]);
            float c = bf2f(PF[(ir >> 6) * 128 + j]);
            sum += fabsf(a - c);
        }
    }
    __shared__ float red[256];
    red[tid] = sum;
    __syncthreads();
    for (int ofs = 128; ofs > 0; ofs >>= 1) {
        if (tid < ofs) red[tid] += red[tid + ofs];
        __syncthreads();
    }
    if (tid == 0) atomicAdd(accum, red[0]);
}

// ---------------------------------------------------------------------------
// K6: finalize + canary + dual-format store (proven r4; canary s3 now segG)
__global__ __launch_bounds__(256) void k_final(
    const float* __restrict__ C, const float* __restrict__ bands,
    const float* __restrict__ segG, const float* __restrict__ topv,
    const float* __restrict__ accum, unsigned* __restrict__ out)
{
    const int tid = threadIdx.x;
    float s1 = 0.f, s2 = 0.f, s3 = 0.f, s4 = 0.f;
    for (int i = tid; i < 32768; i += 256) s1 += fabsf(C[i]);
    for (int i = tid; i < 512;   i += 256) s2 += fabsf(bands[64 + i]);
    for (int i = tid; i < 4096;  i += 256) s3 += fabsf(segG[i]);
    for (int i = tid; i < 128;   i += 256) s4 += fabsf(topv[i]);
    __shared__ float r1[256], r2[256], r3[256], r4[256];
    r1[tid] = s1; r2[tid] = s2; r3[tid] = s3; r4[tid] = s4;
    __syncthreads();
    for (int ofs = 128; ofs > 0; ofs >>= 1) {
        if (tid < ofs) {
            r1[tid] += r1[tid + ofs]; r2[tid] += r2[tid + ofs];
            r3[tid] += r3[tid + ofs]; r4[tid] += r4[tid + ofs];
        }
        __syncthreads();
    }
    if (tid == 0) {
        float L = accum[0] * (1.0f / 1835008.0f);
        unsigned lu = __float_as_uint(L);
        bool isnanL = ((lu & 0x7F800000u) == 0x7F800000u) && (lu & 0x007FFFFFu);
        float code;
        if      (r1[0] < 1e-3f)  code = 100.f;
        else if (r2[0] < 1e-6f)  code = 200.f;
        else if (r3[0] < 1e-6f)  code = 300.f;
        else if (r4[0] < 1e-9f)  code = 350.f;
        else if (isnanL)         code = 500.f;
        else if (L == 0.f)       code = 400.f;
        else if (fabsf(L) < 1e-6f) code = 600.f;
        else                     code = L;
        unsigned fb = __float_as_uint(code);
        unsigned hb = (fb + 0x7FFFu + ((fb >> 16) & 1u)) >> 16;
        out[0] = (hb << 16) | hb;
    }
}

// ---------------------------------------------------------------------------
extern "C" void kernel_launch(void* const* d_in, const int* in_sizes, int n_in,
                              void* d_out, int out_size, void* d_ws, size_t ws_size,
                              hipStream_t stream)
{
    float* C      = (float*)d_ws;                          // 524288 f
    float* bands  = C + (size_t)NSIG * NBINS * 2;          // 1047552 f
    float* segG   = bands + (size_t)NSIG * BAND_STRIDE;    // 917504 f
    float* topv   = segG + (size_t)NSIG * NBANDS * 64 * 128; // 14336 f
    int*   topi   = (int*)(topv + (size_t)NSIG * NBANDS * K_TOP);
    float* accum  = (float*)(topi + (size_t)NSIG * NBANDS * K_TOP);
    __hip_bfloat16* staged = (__hip_bfloat16*)(accum + 4);  // 16B-aligned
    float* TG = (float*)(staged + ST_TOT);   // T and G alias (T dead before G)
    float* T  = TG;
    float* G  = TG;

    const __hip_bfloat16* xstage = staged + ST_X;
    const __hip_bfloat16* fst    = staged + ST_F;
    const __hip_bfloat16* pts    = staged + ST_PT;
    const __hip_bfloat16* pfs    = staged + ST_PF;

    hipMemsetAsync(d_out, 0x3F, 4, stream);   // no-kernel sentinel

    k_stage  <<<dim3((ST_TOT + 255) / 256 + 1), 256, 0, stream>>>(
                 d_in[0], d_in[1], d_in[2], d_in[3], d_in[4],
                 staged, bands, accum);
    k_fwd1   <<<dim3(8, NSIG),        256, 0, stream>>>(xstage, T);
    k_fwd2   <<<dim3(128, NSIG),      128, 0, stream>>>(T, C);
    k_synthA <<<dim3(254, NSIG),      256, 0, stream>>>(C, G);
    k_synthB <<<dim3(254, NSIG),      256, 0, stream>>>(C, G, bands);
    k_conv   <<<dim3(144, NSIG),      256, 0, stream>>>(bands, fst, segG);
    k_topk   <<<dim3(NBANDS, NSIG),   256, 0, stream>>>(segG, topv, topi);
    k_loss   <<<dim3(NBANDS, 8),      256, 0, stream>>>(topv, topi, pts, pfs, accum);
    k_final  <<<1, 256, 0, stream>>>(C, bands, segG, topv, accum,
                                     (unsigned*)d_out);
}

// Round 8
// 459.028 us; speedup vs baseline: 1.3665x; 1.3665x over previous
//
#include <hip/hip_runtime.h>
#include <hip/hip_bf16.h>

#define N_SAMP    32768
#define NBINS     16384
#define NSIG      16
#define NBANDS    7
#define K_TOP     128
// padded per-signal band buffer: 64 zero-floats of guard before each band
// band i: size s=512<<i, payload offset poff(i) = 64*(i+1) + 512*((1<<i)-1)
#define BAND_STRIDE 65472   // 448 pad + 65024 payload

// staged bf16 layout: [x 16x32768 | filters 4096 | PT 8192 | PF 8192]
#define ST_X   0
#define ST_F   524288
#define ST_PT  528384
#define ST_PF  536576
#define ST_TOT 544864

#define TWO_PI 6.283185307179586f

typedef __attribute__((ext_vector_type(8))) short bf16x8;
typedef __attribute__((ext_vector_type(4))) float f32x4;

__device__ __forceinline__ float bf2f(__hip_bfloat16 v) { return __bfloat162float(v); }

// order-preserving float->uint encoding (monotone)
__device__ __forceinline__ unsigned encf(float f) {
    unsigned u = __float_as_uint(f);
    return (u & 0x80000000u) ? ~u : (u | 0x80000000u);
}
__device__ __forceinline__ float decf(unsigned u) {
    return __uint_as_float((u & 0x80000000u) ? (u ^ 0x80000000u) : ~u);
}

// per-band two-step split constants: M = cnt = (b==0?256:s/4) = M1*M2, L = s/M1
__device__ __forceinline__ int band_M1sh(int b) { return b < 3 ? 4 : (b < 4 ? 5 : 6); }
__device__ __forceinline__ int band_Lsh(int b) {
    return b == 0 ? 5 : (b == 1 ? 6 : (b < 5 ? 7 : (b == 5 ? 8 : 9)));
}
__device__ __forceinline__ int band_M2(int b) {
    return b < 2 ? 16 : (b < 5 ? 32 : (b == 5 ? 64 : 128));
}

// ---------------------------------------------------------------------------
// K_stage: detect dtype per-block + canonicalize inputs to bf16 staging;
// tail block zeroes band guards + accum. (proven r7)
__global__ __launch_bounds__(256) void k_stage(
    const void* __restrict__ t, const void* __restrict__ r,
    const void* __restrict__ f, const void* __restrict__ pt,
    const void* __restrict__ pf,
    __hip_bfloat16* __restrict__ staged,
    float* __restrict__ bands, float* __restrict__ accum)
{
    const int tid = threadIdx.x;
    const int bx  = blockIdx.x;
    if (bx == (ST_TOT + 255) / 256) {
        for (int i = tid; i < NSIG * 448; i += 256) {
            int sig = i / 448, rem = i - sig * 448;
            int g = rem >> 6, j = rem & 63;
            int off = 64 * g + 512 * ((1 << g) - 1);
            bands[(size_t)sig * BAND_STRIDE + off + j] = 0.f;
        }
        if (tid == 0) accum[0] = 0.f;
        return;
    }
    float pv = bf2f(((const __hip_bfloat16*)t)[tid & 63]);
    int bad = (fabsf(pv) > 1e8f) || (pv != pv);
    unsigned long long m = __ballot(bad);
    const int isf32 = (m != 0ull);
    const int id = bx * 256 + tid;
    if (id >= ST_TOT) return;
    const void* src; int idx;
    if (id < 262144)      { src = t;  idx = id; }
    else if (id < ST_F)   { src = r;  idx = id - 262144; }
    else if (id < ST_PT)  { src = f;  idx = id - ST_F; }
    else if (id < ST_PF)  { src = pt; idx = id - ST_PT; }
    else                  { src = pf; idx = id - ST_PF; }
    float v = isf32 ? ((const float*)src)[idx]
                    : bf2f(((const __hip_bfloat16*)src)[idx]);
    staged[id] = __float2bfloat16(v);
}

// ---------------------------------------------------------------------------
// Forward rfft via four-step: N = 128 x 256 (proven r5); now 8 k1/block
// (256 blocks) for occupancy.
__global__ __launch_bounds__(256) void k_fwd1(
    const __hip_bfloat16* __restrict__ xstage, float* __restrict__ T)
{
    const int n2  = threadIdx.x;
    const int sig = blockIdx.y;
    const int k1b = blockIdx.x * 8;           // 8 k1 per block
    const __hip_bfloat16* x = xstage + (size_t)sig * N_SAMP;
    __shared__ float ct[128], st[128];
    if (n2 < 128) {
        float sv, cv;
        sincosf(TWO_PI * (float)n2 * (1.f / 128.f), &sv, &cv);
        ct[n2] = cv; st[n2] = sv;
    }
    __syncthreads();
    float ar[8], ai[8];
    #pragma unroll
    for (int q = 0; q < 8; ++q) { ar[q] = 0.f; ai[q] = 0.f; }
    for (int n1 = 0; n1 < 128; ++n1) {
        float xv = bf2f(x[n1 * 256 + n2]);
        #pragma unroll
        for (int q = 0; q < 8; ++q) {
            int t = (n1 * (k1b + q)) & 127;   // W128^{n1 k1} = (ct, -st)
            ar[q] = fmaf(xv,  ct[t], ar[q]);
            ai[q] = fmaf(xv, -st[t], ai[q]);
        }
    }
    float2* To = (float2*)T + (size_t)sig * 128 * 256;
    #pragma unroll
    for (int q = 0; q < 8; ++q) {
        int k1 = k1b + q;
        float sv, cv;                          // e^{-i th} = (cv, -sv)
        sincosf((TWO_PI / 32768.f) * (float)(n2 * k1), &sv, &cv);
        float Tr = ar[q] * cv + ai[q] * sv;
        float Ti = ai[q] * cv - ar[q] * sv;
        To[(size_t)k1 * 256 + n2] = make_float2(Tr, Ti);
    }
}

__global__ __launch_bounds__(128) void k_fwd2(
    const float* __restrict__ T, float* __restrict__ C)
{
    const int k2  = threadIdx.x;              // < 128
    const int k1  = blockIdx.x;
    const int sig = blockIdx.y;
    __shared__ float2 Ts[256];
    const float2* Tin = (const float2*)T + ((size_t)sig * 128 + k1) * 256;
    for (int i = k2; i < 256; i += 128) Ts[i] = Tin[i];
    __syncthreads();
    float sp, cp;
    sincosf(TWO_PI * (float)k2 * (1.f / 256.f), &sp, &cp);  // step = (cp,-sp)
    float er = 1.f, ei = 0.f, Xr = 0.f, Xi = 0.f;
    for (int n2 = 0; n2 < 256; ++n2) {
        float2 t = Ts[n2];
        Xr = fmaf(t.x, er, Xr); Xr = fmaf(-t.y, ei, Xr);
        Xi = fmaf(t.x, ei, Xi); Xi = fmaf( t.y, er, Xi);
        float nr = er * cp + ei * sp;
        ei       = ei * cp - er * sp;
        er = nr;
    }
    const float inv = 5.5242717280199030e-3f;   // 1/sqrt(32768)
    float2* Co = (float2*)C + (size_t)sig * NBINS;
    Co[k1 + 128 * k2] = make_float2(Xr * inv, Xi * inv);
}

// ---------------------------------------------------------------------------
// Band synthesis two-step (proven r5)
__global__ __launch_bounds__(256) void k_synthA(
    const float* __restrict__ C, float* __restrict__ G)
{
    const int tid = threadIdx.x;
    const int sig = blockIdx.y;
    int r = blockIdx.x;                 // band b owns (2<<b) blocks
    int band = 0;
    while (r >= (2 << band)) { r -= (2 << band); ++band; }
    const int s    = 512 << band;
    const int idx  = r * 256 + tid;
    const int m1sh = band_M1sh(band);
    const int lsh  = band_Lsh(band);
    const int M2   = band_M2(band);
    const int L    = 1 << lsh;
    const int a    = (band == 0) ? 0 : (128 << band);
    const int j1   = idx >> lsh;
    const int m    = idx & (L - 1);
    const float2* D = (const float2*)C + (size_t)sig * NBINS + a;
    float sv, cv;                       // rotation step e^{+2pi i m/L}
    sincosf(TWO_PI * (float)m / (float)L, &sv, &cv);
    float er = 1.f, ei = 0.f, gr = 0.f, gi = 0.f;
    for (int j2 = 0; j2 < M2; ++j2) {
        float2 d = D[j1 + (j2 << m1sh)];
        gr += d.x * er - d.y * ei;
        gi += d.x * ei + d.y * er;
        float nr = er * cv - ei * sv;
        ei       = er * sv + ei * cv;
        er = nr;
    }
    const float sc = 2.f * rsqrtf((float)s);
    float2* Go = (float2*)G + (size_t)sig * 65024 + 512 * ((1 << band) - 1);
    Go[idx] = make_float2(gr * sc, gi * sc);
}

__global__ __launch_bounds__(256) void k_synthB(
    const float* __restrict__ C, const float* __restrict__ G,
    float* __restrict__ bands)
{
    const int tid = threadIdx.x;
    const int sig = blockIdx.y;
    int r = blockIdx.x;
    int band = 0;
    while (r >= (2 << band)) { r -= (2 << band); ++band; }
    const int s    = 512 << band;
    const int n    = r * 256 + tid;
    const int M1   = 1 << band_M1sh(band);
    const int lsh  = band_Lsh(band);
    const int m    = n & ((1 << lsh) - 1);
    const float2* Gi = (const float2*)G + (size_t)sig * 65024 + 512 * ((1 << band) - 1);
    float sv, cv;                       // rotation step e^{+2pi i n/s}
    sincosf(TWO_PI * (float)n / (float)s, &sv, &cv);
    float er = 1.f, ei = 0.f, zr = 0.f, zi = 0.f;
    for (int j1 = 0; j1 < M1; ++j1) {
        float2 g = Gi[(j1 << lsh) + m];
        zr += g.x * er - g.y * ei;
        zi += g.x * ei + g.y * er;
        float nr = er * cv - ei * sv;
        ei       = er * sv + ei * cv;
        er = nr;
    }
    float val;
    if (band == 0) {
        val = zr - C[(size_t)sig * NBINS * 2] * 0.04419417382415922f; // 1/sqrt(512)
    } else {
        switch (n & 3) {                // Re(i^n * z)
            case 0:  val =  zr; break;
            case 1:  val = -zi; break;
            case 2:  val = -zr; break;
            default: val =  zi; break;
        }
    }
    const int poff = 64 * (band + 1) + 512 * ((1 << band) - 1);
    bands[(size_t)sig * BAND_STRIDE + poff + n] = val;
}

// ---------------------------------------------------------------------------
// K3: MFMA conv + fused segment-max pooling.
// One block = one 512-sample chunk (127 uniform chunks/sig). D = A*B:
// A (16x32) = x Toeplitz frag: A[m=t=lane&15][k=quad*8+j] = x[t0+t-j0-k].
// Reversed x in LDS with 8 phase-shifted copies -> per-lane aligned b128.
// B (32x16) = filters: B[k][n=f=lane&15] = filt[f][j0+k], contiguous b128.
// D rows (quad*4+reg) = 4 consecutive t at fixed f -> pooling = in-lane max
// + shfl_xor(16/32); unique-writer stores to segG. No atomics, no C LDS.
__global__ __launch_bounds__(256) void k_conv(
    const float* __restrict__ bands,
    const __hip_bfloat16* __restrict__ filters,
    float* __restrict__ segG)
{
    const int tid  = threadIdx.x;
    const int sig  = blockIdx.y;
    const int c    = blockIdx.x;               // 0..126
    const int band = 31 - __clz(c + 1);        // chunks per band = 1<<band
    const int cidx = c + 1 - (1 << band);
    const int poff = 64 * (band + 1) + 512 * ((1 << band) - 1);
    const float* bp = bands + (size_t)sig * BAND_STRIDE + poff + cidx * 512;

    __shared__ __align__(16) __hip_bfloat16 xr[8][584]; // 8 shifted reversed copies
    __shared__ float segP[64 * 4];                      // band-6 wave partials

    // stage: xr_p[p][m] = xr[m+p], xr[i] = x[511-i] (x rel. chunk, guard ok)
    for (int i = tid; i < 576; i += 256) {
        __hip_bfloat16 b = __float2bfloat16(bp[511 - i]);
        #pragma unroll
        for (int p = 0; p < 8; ++p) {
            int idx = i - p;
            if (idx >= 0) xr[p][idx] = b;
        }
    }
    __syncthreads();

    const int tl   = tid & 15;
    const int quad = (tid >> 4) & 3;
    const int wave = tid >> 6;

    // filter B-frags (K-halves j0=0,32)
    bf16x8 bf0[4], bf1[4];
    #pragma unroll
    for (int ft = 0; ft < 4; ++ft) {
        const __hip_bfloat16* fp = filters + ((ft * 16 + tl) * 64 + quad * 8);
        bf0[ft] = *(const bf16x8*)(fp);
        bf1[ft] = *(const bf16x8*)(fp + 32);
    }

    // x A-frag pointer: s = 511 - t0 - tl + j0 + 8*quad; addr = p*584 + (s&~7)
    int s0 = 511 - wave * 128 - tl + 8 * quad;
    const __hip_bfloat16* xp = &xr[0][0] + (s0 & 7) * 584 + (s0 & ~7);

    const int spc = 512 >> (2 + band);          // segs per chunk
    float* segO = segG + (size_t)(sig * NBANDS + band) * 64 * 128 + cidx * spc;

    const float NEG = -3.4e38f;
    float run0 = NEG, run1 = NEG, run2 = NEG, run3 = NEG;
    const int per = (band >= 2) ? (1 << (band - 2)) : 1;   // tiles per segment

    for (int it = 0; it < 8; ++it) {
        const int t0 = wave * 128 + it * 16;
        bf16x8 a0 = *(const bf16x8*)(xp);
        bf16x8 a1 = *(const bf16x8*)(xp + 32);
        xp -= 16;
        f32x4 ac0 = {0.f,0.f,0.f,0.f}, ac1 = ac0, ac2 = ac0, ac3 = ac0;
        ac0 = __builtin_amdgcn_mfma_f32_16x16x32_bf16(a0, bf0[0], ac0, 0, 0, 0);
        ac0 = __builtin_amdgcn_mfma_f32_16x16x32_bf16(a1, bf1[0], ac0, 0, 0, 0);
        ac1 = __builtin_amdgcn_mfma_f32_16x16x32_bf16(a0, bf0[1], ac1, 0, 0, 0);
        ac1 = __builtin_amdgcn_mfma_f32_16x16x32_bf16(a1, bf1[1], ac1, 0, 0, 0);
        ac2 = __builtin_amdgcn_mfma_f32_16x16x32_bf16(a0, bf0[2], ac2, 0, 0, 0);
        ac2 = __builtin_amdgcn_mfma_f32_16x16x32_bf16(a1, bf1[2], ac2, 0, 0, 0);
        ac3 = __builtin_amdgcn_mfma_f32_16x16x32_bf16(a0, bf0[3], ac3, 0, 0, 0);
        ac3 = __builtin_amdgcn_mfma_f32_16x16x32_bf16(a1, bf1[3], ac3, 0, 0, 0);
        // in-lane max over 4 consecutive t (regs), per f-tile
        float m0 = fmaxf(fmaxf(ac0[0], ac0[1]), fmaxf(ac0[2], ac0[3]));
        float m1 = fmaxf(fmaxf(ac1[0], ac1[1]), fmaxf(ac1[2], ac1[3]));
        float m2 = fmaxf(fmaxf(ac2[0], ac2[1]), fmaxf(ac2[2], ac2[3]));
        float m3 = fmaxf(fmaxf(ac3[0], ac3[1]), fmaxf(ac3[2], ac3[3]));
        if (band == 0) {                // seg width 4 = one quad's regs
            int sb = (t0 >> 2) + quad;
            segO[(tl     ) * 128 + sb] = m0;
            segO[(tl + 16) * 128 + sb] = m1;
            segO[(tl + 32) * 128 + sb] = m2;
            segO[(tl + 48) * 128 + sb] = m3;
        } else if (band == 1) {         // seg width 8 = quad pair
            m0 = fmaxf(m0, __shfl_xor(m0, 16));
            m1 = fmaxf(m1, __shfl_xor(m1, 16));
            m2 = fmaxf(m2, __shfl_xor(m2, 16));
            m3 = fmaxf(m3, __shfl_xor(m3, 16));
            if ((quad & 1) == 0) {
                int sb = (t0 >> 3) + (quad >> 1);
                segO[(tl     ) * 128 + sb] = m0;
                segO[(tl + 16) * 128 + sb] = m1;
                segO[(tl + 32) * 128 + sb] = m2;
                segO[(tl + 48) * 128 + sb] = m3;
            }
        } else {                        // full 16-t tile max, accumulate
            m0 = fmaxf(m0, __shfl_xor(m0, 16)); m0 = fmaxf(m0, __shfl_xor(m0, 32));
            m1 = fmaxf(m1, __shfl_xor(m1, 16)); m1 = fmaxf(m1, __shfl_xor(m1, 32));
            m2 = fmaxf(m2, __shfl_xor(m2, 16)); m2 = fmaxf(m2, __shfl_xor(m2, 32));
            m3 = fmaxf(m3, __shfl_xor(m3, 16)); m3 = fmaxf(m3, __shfl_xor(m3, 32));
            run0 = fmaxf(run0, m0); run1 = fmaxf(run1, m1);
            run2 = fmaxf(run2, m2); run3 = fmaxf(run3, m3);
            if (((it + 1) & (per - 1)) == 0) {   // band<=5 boundary (never b6)
                int sb = t0 >> (2 + band);
                float rv = quad == 0 ? run0 : quad == 1 ? run1
                         : quad == 2 ? run2 : run3;
                segO[(tl + 16 * quad) * 128 + sb] = rv;
                run0 = NEG; run1 = NEG; run2 = NEG; run3 = NEG;
            }
        }
    }
    if (band == 6) {                    // seg spans 2 waves: combine via LDS
        float rv = quad == 0 ? run0 : quad == 1 ? run1
                 : quad == 2 ? run2 : run3;
        segP[(tl + 16 * quad) * 4 + wave] = rv;
        __syncthreads();
        if (tid < 128) {
            int f = tid & 63, sg = tid >> 6;
            segO[f * 128 + sg] =
                fmaxf(segP[f * 4 + 2 * sg], segP[f * 4 + 2 * sg + 1]);
        }
    }
}

// ---------------------------------------------------------------------------
// K4: pool (from segG) + stable top-128 of 4096 per (sig,band) (proven r7)
__global__ __launch_bounds__(256) void k_topk(
    const float* __restrict__ segG,
    float* __restrict__ topv, int* __restrict__ topi)
{
    __shared__ unsigned long long keys[4096];
    const int tid = threadIdx.x;
    const int band = blockIdx.x, sig = blockIdx.y;
    const float* segB = segG + (size_t)(sig * NBANDS + band) * 64 * 128;
    for (int i = tid; i < 4096; i += 256) {
        int f = i >> 6, t = i & 63;
        const float* sg = segB + f * 128;
        float m = fmaxf(sg[2 * t], sg[2 * t + 1]);
        if (t > 0)  m = fmaxf(m, sg[2 * t - 1]);
        if (t < 63) m = fmaxf(m, sg[2 * t + 2]);
        keys[i] = ((unsigned long long)encf(m) << 32) | (unsigned)(4095 - i);
    }
    for (int k = 2; k <= 4096; k <<= 1) {
        for (int j = k >> 1; j > 0; j >>= 1) {
            __syncthreads();
            for (int i = tid; i < 4096; i += 256) {
                int l = i ^ j;
                if (l > i) {
                    unsigned long long av = keys[i], bv = keys[l];
                    bool up = ((i & k) == 0);
                    if ((av > bv) == up) { keys[i] = bv; keys[l] = av; }
                }
            }
        }
    }
    __syncthreads();
    if (tid < K_TOP) {
        unsigned long long key = keys[4095 - tid];
        const size_t ob = ((size_t)sig * NBANDS + band) * K_TOP + tid;
        topv[ob] = decf((unsigned)(key >> 32));
        topi[ob] = 4095 - (int)(key & 0xFFFFFFFFu);
    }
}

// ---------------------------------------------------------------------------
// K5: loss partial sums (proven r4)
__global__ __launch_bounds__(256) void k_loss(
    const float* __restrict__ topv, const int* __restrict__ topi,
    const __hip_bfloat16* __restrict__ PT, const __hip_bfloat16* __restrict__ PF,
    float* __restrict__ accum)
{
    const int tid = threadIdx.x;
    const int band = blockIdx.x, b = blockIdx.y;
    const size_t bt = ((size_t)b * NBANDS + band) * K_TOP;
    const size_t br = ((size_t)(8 + b) * NBANDS + band) * K_TOP;
    float sum = 0.f;
    for (int k = 0; k < K_TOP; ++k) {
        float vt = topv[bt + k]; int it = topi[bt + k];
        float vr = topv[br + k]; int ir = topi[br + k];
        if (tid < 128) {
            float a = vt * bf2f(PT[(it & 63) * 128 + tid]);
            float c = vr * bf2f(PT[(ir & 63) * 128 + tid]);
            sum += fabsf(a - c);
        } else {
            int j = tid - 128;
            float a = bf2f(PF[(it >> 6) * 128 + j]);
            float c = bf2f(PF[(ir >> 6) * 128 + j]);
            sum += fabsf(a - c);
        }
    }
    __shared__ float red[256];
    red[tid] = sum;
    __syncthreads();
    for (int ofs = 128; ofs > 0; ofs >>= 1) {
        if (tid < ofs) red[tid] += red[tid + ofs];
        __syncthreads();
    }
    if (tid == 0) atomicAdd(accum, red[0]);
}

// ---------------------------------------------------------------------------
// K6: finalize + canary + dual-format store (proven r4)
__global__ __launch_bounds__(256) void k_final(
    const float* __restrict__ C, const float* __restrict__ bands,
    const float* __restrict__ segG, const float* __restrict__ topv,
    const float* __restrict__ accum, unsigned* __restrict__ out)
{
    const int tid = threadIdx.x;
    float s1 = 0.f, s2 = 0.f, s3 = 0.f, s4 = 0.f;
    for (int i = tid; i < 32768; i += 256) s1 += fabsf(C[i]);
    for (int i = tid; i < 512;   i += 256) s2 += fabsf(bands[64 + i]);
    for (int i = tid; i < 4096;  i += 256) s3 += fabsf(segG[i]);
    for (int i = tid; i < 128;   i += 256) s4 += fabsf(topv[i]);
    __shared__ float r1[256], r2[256], r3[256], r4[256];
    r1[tid] = s1; r2[tid] = s2; r3[tid] = s3; r4[tid] = s4;
    __syncthreads();
    for (int ofs = 128; ofs > 0; ofs >>= 1) {
        if (tid < ofs) {
            r1[tid] += r1[tid + ofs]; r2[tid] += r2[tid + ofs];
            r3[tid] += r3[tid + ofs]; r4[tid] += r4[tid + ofs];
        }
        __syncthreads();
    }
    if (tid == 0) {
        float L = accum[0] * (1.0f / 1835008.0f);
        unsigned lu = __float_as_uint(L);
        bool isnanL = ((lu & 0x7F800000u) == 0x7F800000u) && (lu & 0x007FFFFFu);
        float code;
        if      (r1[0] < 1e-3f)  code = 100.f;
        else if (r2[0] < 1e-6f)  code = 200.f;
        else if (r3[0] < 1e-6f)  code = 300.f;
        else if (r4[0] < 1e-9f)  code = 350.f;
        else if (isnanL)         code = 500.f;
        else if (L == 0.f)       code = 400.f;
        else if (fabsf(L) < 1e-6f) code = 600.f;
        else                     code = L;
        unsigned fb = __float_as_uint(code);
        unsigned hb = (fb + 0x7FFFu + ((fb >> 16) & 1u)) >> 16;
        out[0] = (hb << 16) | hb;
    }
}

// ---------------------------------------------------------------------------
extern "C" void kernel_launch(void* const* d_in, const int* in_sizes, int n_in,
                              void* d_out, int out_size, void* d_ws, size_t ws_size,
                              hipStream_t stream)
{
    float* C      = (float*)d_ws;                          // 524288 f
    float* bands  = C + (size_t)NSIG * NBINS * 2;          // 1047552 f
    float* segG   = bands + (size_t)NSIG * BAND_STRIDE;    // 917504 f
    float* topv   = segG + (size_t)NSIG * NBANDS * 64 * 128; // 14336 f
    int*   topi   = (int*)(topv + (size_t)NSIG * NBANDS * K_TOP);
    float* accum  = (float*)(topi + (size_t)NSIG * NBANDS * K_TOP);
    __hip_bfloat16* staged = (__hip_bfloat16*)(accum + 4);  // 16B-aligned
    float* TG = (float*)(staged + ST_TOT);   // T and G alias (T dead before G)
    float* T  = TG;
    float* G  = TG;

    const __hip_bfloat16* xstage = staged + ST_X;
    const __hip_bfloat16* fst    = staged + ST_F;
    const __hip_bfloat16* pts    = staged + ST_PT;
    const __hip_bfloat16* pfs    = staged + ST_PF;

    hipMemsetAsync(d_out, 0x3F, 4, stream);   // no-kernel sentinel

    k_stage  <<<dim3((ST_TOT + 255) / 256 + 1), 256, 0, stream>>>(
                 d_in[0], d_in[1], d_in[2], d_in[3], d_in[4],
                 staged, bands, accum);
    k_fwd1   <<<dim3(16, NSIG),       256, 0, stream>>>(xstage, T);
    k_fwd2   <<<dim3(128, NSIG),      128, 0, stream>>>(T, C);
    k_synthA <<<dim3(254, NSIG),      256, 0, stream>>>(C, G);
    k_synthB <<<dim3(254, NSIG),      256, 0, stream>>>(C, G, bands);
    k_conv   <<<dim3(127, NSIG),      256, 0, stream>>>(bands, fst, segG);
    k_topk   <<<dim3(NBANDS, NSIG),   256, 0, stream>>>(segG, topv, topi);
    k_loss   <<<dim3(NBANDS, 8),      256, 0, stream>>>(topv, topi, pts, pfs, accum);
    k_final  <<<1, 256, 0, stream>>>(C, bands, segG, topv, accum,
                                     (unsigned*)d_out);
}

// Round 9
// 342.473 us; speedup vs baseline: 1.8315x; 1.3403x over previous
//
#include <hip/hip_runtime.h>
#include <hip/hip_bf16.h>

#define N_SAMP    32768
#define NBINS     16384
#define NSIG      16
#define NBANDS    7
#define K_TOP     128
// padded per-signal band buffer: 64 zero-floats of guard before each band
// band i: size s=512<<i, payload offset poff(i) = 64*(i+1) + 512*((1<<i)-1)
#define BAND_STRIDE 65472   // 448 pad + 65024 payload

// staged bf16 layout: [x 16x32768 | filters 4096 | PT 8192 | PF 8192]
#define ST_X   0
#define ST_F   524288
#define ST_PT  528384
#define ST_PF  536576
#define ST_TOT 544864

#define TWO_PI 6.283185307179586f

typedef __attribute__((ext_vector_type(8))) short bf16x8;
typedef __attribute__((ext_vector_type(4))) float f32x4;

__device__ __forceinline__ float bf2f(__hip_bfloat16 v) { return __bfloat162float(v); }

// order-preserving float->uint encoding (monotone)
__device__ __forceinline__ unsigned encf(float f) {
    unsigned u = __float_as_uint(f);
    return (u & 0x80000000u) ? ~u : (u | 0x80000000u);
}
__device__ __forceinline__ float decf(unsigned u) {
    return __uint_as_float((u & 0x80000000u) ? (u ^ 0x80000000u) : ~u);
}

// per-band two-step split constants: M = cnt = (b==0?256:s/4) = M1*M2, L = s/M1
__device__ __forceinline__ int band_M1sh(int b) { return b < 3 ? 4 : (b < 4 ? 5 : 6); }
__device__ __forceinline__ int band_Lsh(int b) {
    return b == 0 ? 5 : (b == 1 ? 6 : (b < 5 ? 7 : (b == 5 ? 8 : 9)));
}
__device__ __forceinline__ int band_M2(int b) {
    return b < 2 ? 16 : (b < 5 ? 32 : (b == 5 ? 64 : 128));
}

// ---------------------------------------------------------------------------
// K_stage: detect dtype per-block + canonicalize inputs to bf16 staging;
// tail block zeroes band guards + accum. (proven r7)
__global__ __launch_bounds__(256) void k_stage(
    const void* __restrict__ t, const void* __restrict__ r,
    const void* __restrict__ f, const void* __restrict__ pt,
    const void* __restrict__ pf,
    __hip_bfloat16* __restrict__ staged,
    float* __restrict__ bands, float* __restrict__ accum)
{
    const int tid = threadIdx.x;
    const int bx  = blockIdx.x;
    if (bx == (ST_TOT + 255) / 256) {
        for (int i = tid; i < NSIG * 448; i += 256) {
            int sig = i / 448, rem = i - sig * 448;
            int g = rem >> 6, j = rem & 63;
            int off = 64 * g + 512 * ((1 << g) - 1);
            bands[(size_t)sig * BAND_STRIDE + off + j] = 0.f;
        }
        if (tid == 0) accum[0] = 0.f;
        return;
    }
    float pv = bf2f(((const __hip_bfloat16*)t)[tid & 63]);
    int bad = (fabsf(pv) > 1e8f) || (pv != pv);
    unsigned long long m = __ballot(bad);
    const int isf32 = (m != 0ull);
    const int id = bx * 256 + tid;
    if (id >= ST_TOT) return;
    const void* src; int idx;
    if (id < 262144)      { src = t;  idx = id; }
    else if (id < ST_F)   { src = r;  idx = id - 262144; }
    else if (id < ST_PT)  { src = f;  idx = id - ST_F; }
    else if (id < ST_PF)  { src = pt; idx = id - ST_PT; }
    else                  { src = pf; idx = id - ST_PF; }
    float v = isf32 ? ((const float*)src)[idx]
                    : bf2f(((const __hip_bfloat16*)src)[idx]);
    staged[id] = __float2bfloat16(v);
}

// ---------------------------------------------------------------------------
// Forward rfft via four-step: N = 128 x 256 (proven r5/r8)
__global__ __launch_bounds__(256) void k_fwd1(
    const __hip_bfloat16* __restrict__ xstage, float* __restrict__ T)
{
    const int n2  = threadIdx.x;
    const int sig = blockIdx.y;
    const int k1b = blockIdx.x * 8;           // 8 k1 per block
    const __hip_bfloat16* x = xstage + (size_t)sig * N_SAMP;
    __shared__ float ct[128], st[128];
    if (n2 < 128) {
        float sv, cv;
        sincosf(TWO_PI * (float)n2 * (1.f / 128.f), &sv, &cv);
        ct[n2] = cv; st[n2] = sv;
    }
    __syncthreads();
    float ar[8], ai[8];
    #pragma unroll
    for (int q = 0; q < 8; ++q) { ar[q] = 0.f; ai[q] = 0.f; }
    for (int n1 = 0; n1 < 128; ++n1) {
        float xv = bf2f(x[n1 * 256 + n2]);
        #pragma unroll
        for (int q = 0; q < 8; ++q) {
            int t = (n1 * (k1b + q)) & 127;   // W128^{n1 k1} = (ct, -st)
            ar[q] = fmaf(xv,  ct[t], ar[q]);
            ai[q] = fmaf(xv, -st[t], ai[q]);
        }
    }
    float2* To = (float2*)T + (size_t)sig * 128 * 256;
    #pragma unroll
    for (int q = 0; q < 8; ++q) {
        int k1 = k1b + q;
        float sv, cv;                          // e^{-i th} = (cv, -sv)
        sincosf((TWO_PI / 32768.f) * (float)(n2 * k1), &sv, &cv);
        float Tr = ar[q] * cv + ai[q] * sv;
        float Ti = ai[q] * cv - ar[q] * sv;
        To[(size_t)k1 * 256 + n2] = make_float2(Tr, Ti);
    }
}

__global__ __launch_bounds__(128) void k_fwd2(
    const float* __restrict__ T, float* __restrict__ C)
{
    const int k2  = threadIdx.x;              // < 128
    const int k1  = blockIdx.x;
    const int sig = blockIdx.y;
    __shared__ float2 Ts[256];
    const float2* Tin = (const float2*)T + ((size_t)sig * 128 + k1) * 256;
    for (int i = k2; i < 256; i += 128) Ts[i] = Tin[i];
    __syncthreads();
    float sp, cp;
    sincosf(TWO_PI * (float)k2 * (1.f / 256.f), &sp, &cp);  // step = (cp,-sp)
    float er = 1.f, ei = 0.f, Xr = 0.f, Xi = 0.f;
    for (int n2 = 0; n2 < 256; ++n2) {
        float2 t = Ts[n2];
        Xr = fmaf(t.x, er, Xr); Xr = fmaf(-t.y, ei, Xr);
        Xi = fmaf(t.x, ei, Xi); Xi = fmaf( t.y, er, Xi);
        float nr = er * cp + ei * sp;
        ei       = ei * cp - er * sp;
        er = nr;
    }
    const float inv = 5.5242717280199030e-3f;   // 1/sqrt(32768)
    float2* Co = (float2*)C + (size_t)sig * NBINS;
    Co[k1 + 128 * k2] = make_float2(Xr * inv, Xi * inv);
}

// ---------------------------------------------------------------------------
// Band synthesis two-step (proven r5)
__global__ __launch_bounds__(256) void k_synthA(
    const float* __restrict__ C, float* __restrict__ G)
{
    const int tid = threadIdx.x;
    const int sig = blockIdx.y;
    int r = blockIdx.x;                 // band b owns (2<<b) blocks
    int band = 0;
    while (r >= (2 << band)) { r -= (2 << band); ++band; }
    const int s    = 512 << band;
    const int idx  = r * 256 + tid;
    const int m1sh = band_M1sh(band);
    const int lsh  = band_Lsh(band);
    const int M2   = band_M2(band);
    const int L    = 1 << lsh;
    const int a    = (band == 0) ? 0 : (128 << band);
    const int j1   = idx >> lsh;
    const int m    = idx & (L - 1);
    const float2* D = (const float2*)C + (size_t)sig * NBINS + a;
    float sv, cv;                       // rotation step e^{+2pi i m/L}
    sincosf(TWO_PI * (float)m / (float)L, &sv, &cv);
    float er = 1.f, ei = 0.f, gr = 0.f, gi = 0.f;
    for (int j2 = 0; j2 < M2; ++j2) {
        float2 d = D[j1 + (j2 << m1sh)];
        gr += d.x * er - d.y * ei;
        gi += d.x * ei + d.y * er;
        float nr = er * cv - ei * sv;
        ei       = er * sv + ei * cv;
        er = nr;
    }
    const float sc = 2.f * rsqrtf((float)s);
    float2* Go = (float2*)G + (size_t)sig * 65024 + 512 * ((1 << band) - 1);
    Go[idx] = make_float2(gr * sc, gi * sc);
}

__global__ __launch_bounds__(256) void k_synthB(
    const float* __restrict__ C, const float* __restrict__ G,
    float* __restrict__ bands)
{
    const int tid = threadIdx.x;
    const int sig = blockIdx.y;
    int r = blockIdx.x;
    int band = 0;
    while (r >= (2 << band)) { r -= (2 << band); ++band; }
    const int s    = 512 << band;
    const int n    = r * 256 + tid;
    const int M1   = 1 << band_M1sh(band);
    const int lsh  = band_Lsh(band);
    const int m    = n & ((1 << lsh) - 1);
    const float2* Gi = (const float2*)G + (size_t)sig * 65024 + 512 * ((1 << band) - 1);
    float sv, cv;                       // rotation step e^{+2pi i n/s}
    sincosf(TWO_PI * (float)n / (float)s, &sv, &cv);
    float er = 1.f, ei = 0.f, zr = 0.f, zi = 0.f;
    for (int j1 = 0; j1 < M1; ++j1) {
        float2 g = Gi[(j1 << lsh) + m];
        zr += g.x * er - g.y * ei;
        zi += g.x * ei + g.y * er;
        float nr = er * cv - ei * sv;
        ei       = er * sv + ei * cv;
        er = nr;
    }
    float val;
    if (band == 0) {
        val = zr - C[(size_t)sig * NBINS * 2] * 0.04419417382415922f; // 1/sqrt(512)
    } else {
        switch (n & 3) {                // Re(i^n * z)
            case 0:  val =  zr; break;
            case 1:  val = -zi; break;
            case 2:  val = -zr; break;
            default: val =  zi; break;
        }
    }
    const int poff = 64 * (band + 1) + 512 * ((1 << band) - 1);
    bands[(size_t)sig * BAND_STRIDE + poff + n] = val;
}

// ---------------------------------------------------------------------------
// K3: MFMA conv + fused segment-max pooling (proven r8, bit-exact)
__global__ __launch_bounds__(256) void k_conv(
    const float* __restrict__ bands,
    const __hip_bfloat16* __restrict__ filters,
    float* __restrict__ segG)
{
    const int tid  = threadIdx.x;
    const int sig  = blockIdx.y;
    const int c    = blockIdx.x;               // 0..126
    const int band = 31 - __clz(c + 1);        // chunks per band = 1<<band
    const int cidx = c + 1 - (1 << band);
    const int poff = 64 * (band + 1) + 512 * ((1 << band) - 1);
    const float* bp = bands + (size_t)sig * BAND_STRIDE + poff + cidx * 512;

    __shared__ __align__(16) __hip_bfloat16 xr[8][584]; // 8 shifted reversed copies
    __shared__ float segP[64 * 4];                      // band-6 wave partials

    for (int i = tid; i < 576; i += 256) {
        __hip_bfloat16 b = __float2bfloat16(bp[511 - i]);
        #pragma unroll
        for (int p = 0; p < 8; ++p) {
            int idx = i - p;
            if (idx >= 0) xr[p][idx] = b;
        }
    }
    __syncthreads();

    const int tl   = tid & 15;
    const int quad = (tid >> 4) & 3;
    const int wave = tid >> 6;

    bf16x8 bf0[4], bf1[4];
    #pragma unroll
    for (int ft = 0; ft < 4; ++ft) {
        const __hip_bfloat16* fp = filters + ((ft * 16 + tl) * 64 + quad * 8);
        bf0[ft] = *(const bf16x8*)(fp);
        bf1[ft] = *(const bf16x8*)(fp + 32);
    }

    int s0 = 511 - wave * 128 - tl + 8 * quad;
    const __hip_bfloat16* xp = &xr[0][0] + (s0 & 7) * 584 + (s0 & ~7);

    const int spc = 512 >> (2 + band);          // segs per chunk
    float* segO = segG + (size_t)(sig * NBANDS + band) * 64 * 128 + cidx * spc;

    const float NEG = -3.4e38f;
    float run0 = NEG, run1 = NEG, run2 = NEG, run3 = NEG;
    const int per = (band >= 2) ? (1 << (band - 2)) : 1;   // tiles per segment

    for (int it = 0; it < 8; ++it) {
        const int t0 = wave * 128 + it * 16;
        bf16x8 a0 = *(const bf16x8*)(xp);
        bf16x8 a1 = *(const bf16x8*)(xp + 32);
        xp -= 16;
        f32x4 ac0 = {0.f,0.f,0.f,0.f}, ac1 = ac0, ac2 = ac0, ac3 = ac0;
        ac0 = __builtin_amdgcn_mfma_f32_16x16x32_bf16(a0, bf0[0], ac0, 0, 0, 0);
        ac0 = __builtin_amdgcn_mfma_f32_16x16x32_bf16(a1, bf1[0], ac0, 0, 0, 0);
        ac1 = __builtin_amdgcn_mfma_f32_16x16x32_bf16(a0, bf0[1], ac1, 0, 0, 0);
        ac1 = __builtin_amdgcn_mfma_f32_16x16x32_bf16(a1, bf1[1], ac1, 0, 0, 0);
        ac2 = __builtin_amdgcn_mfma_f32_16x16x32_bf16(a0, bf0[2], ac2, 0, 0, 0);
        ac2 = __builtin_amdgcn_mfma_f32_16x16x32_bf16(a1, bf1[2], ac2, 0, 0, 0);
        ac3 = __builtin_amdgcn_mfma_f32_16x16x32_bf16(a0, bf0[3], ac3, 0, 0, 0);
        ac3 = __builtin_amdgcn_mfma_f32_16x16x32_bf16(a1, bf1[3], ac3, 0, 0, 0);
        float m0 = fmaxf(fmaxf(ac0[0], ac0[1]), fmaxf(ac0[2], ac0[3]));
        float m1 = fmaxf(fmaxf(ac1[0], ac1[1]), fmaxf(ac1[2], ac1[3]));
        float m2 = fmaxf(fmaxf(ac2[0], ac2[1]), fmaxf(ac2[2], ac2[3]));
        float m3 = fmaxf(fmaxf(ac3[0], ac3[1]), fmaxf(ac3[2], ac3[3]));
        if (band == 0) {
            int sb = (t0 >> 2) + quad;
            segO[(tl     ) * 128 + sb] = m0;
            segO[(tl + 16) * 128 + sb] = m1;
            segO[(tl + 32) * 128 + sb] = m2;
            segO[(tl + 48) * 128 + sb] = m3;
        } else if (band == 1) {
            m0 = fmaxf(m0, __shfl_xor(m0, 16));
            m1 = fmaxf(m1, __shfl_xor(m1, 16));
            m2 = fmaxf(m2, __shfl_xor(m2, 16));
            m3 = fmaxf(m3, __shfl_xor(m3, 16));
            if ((quad & 1) == 0) {
                int sb = (t0 >> 3) + (quad >> 1);
                segO[(tl     ) * 128 + sb] = m0;
                segO[(tl + 16) * 128 + sb] = m1;
                segO[(tl + 32) * 128 + sb] = m2;
                segO[(tl + 48) * 128 + sb] = m3;
            }
        } else {
            m0 = fmaxf(m0, __shfl_xor(m0, 16)); m0 = fmaxf(m0, __shfl_xor(m0, 32));
            m1 = fmaxf(m1, __shfl_xor(m1, 16)); m1 = fmaxf(m1, __shfl_xor(m1, 32));
            m2 = fmaxf(m2, __shfl_xor(m2, 16)); m2 = fmaxf(m2, __shfl_xor(m2, 32));
            m3 = fmaxf(m3, __shfl_xor(m3, 16)); m3 = fmaxf(m3, __shfl_xor(m3, 32));
            run0 = fmaxf(run0, m0); run1 = fmaxf(run1, m1);
            run2 = fmaxf(run2, m2); run3 = fmaxf(run3, m3);
            if (((it + 1) & (per - 1)) == 0) {
                int sb = t0 >> (2 + band);
                float rv = quad == 0 ? run0 : quad == 1 ? run1
                         : quad == 2 ? run2 : run3;
                segO[(tl + 16 * quad) * 128 + sb] = rv;
                run0 = NEG; run1 = NEG; run2 = NEG; run3 = NEG;
            }
        }
    }
    if (band == 6) {
        float rv = quad == 0 ? run0 : quad == 1 ? run1
                 : quad == 2 ? run2 : run3;
        segP[(tl + 16 * quad) * 4 + wave] = rv;
        __syncthreads();
        if (tid < 128) {
            int f = tid & 63, sg = tid >> 6;
            segO[f * 128 + sg] =
                fmaxf(segP[f * 4 + 2 * sg], segP[f * 4 + 2 * sg + 1]);
        }
    }
}

// ---------------------------------------------------------------------------
// K4: pool + top-128 via byte-wise RADIX SELECT + small bitonic sort.
// Keys (16/thread, registers): (enc(pooled)<<32)|(4095-i) — unique.
// Level loop: 256-bin histogram of current byte among keys matching the
// boundary prefix; suffix-scan; pick bin B with cumGT<128<=cumGE. Stop when
// surviving set (nAbove+bin count) fits 512; compact; sort 512; emit 128.
// Exact + stable: identical result to full sort (keys unique, monotone).
__global__ __launch_bounds__(256) void k_topk(
    const float* __restrict__ segG,
    float* __restrict__ topv, int* __restrict__ topi)
{
    const int tid = threadIdx.x;
    const int band = blockIdx.x, sig = blockIdx.y;
    const float* segB = segG + (size_t)(sig * NBANDS + band) * 64 * 128;

    __shared__ unsigned hist[256];
    __shared__ unsigned scan[256];
    __shared__ unsigned long long list[512];
    __shared__ int sh_B, sh_nA, sh_cnt, sh_num;

    unsigned long long kk[16];
    #pragma unroll
    for (int q = 0; q < 16; ++q) {
        int i = q * 256 + tid;
        int f = i >> 6, t = i & 63;
        const float* sg = segB + f * 128;
        float m = fmaxf(sg[2 * t], sg[2 * t + 1]);
        if (t > 0)  m = fmaxf(m, sg[2 * t - 1]);
        if (t < 63) m = fmaxf(m, sg[2 * t + 2]);
        kk[q] = ((unsigned long long)encf(m) << 32) | (unsigned)(4095 - i);
    }

    int shift = 56;
    unsigned long long prefix = 0;
    int nA = 0;
    for (int lev = 0; lev < 8; ++lev) {
        hist[tid] = 0;
        __syncthreads();
        #pragma unroll
        for (int q = 0; q < 16; ++q) {
            bool inpre = (lev == 0) || ((kk[q] >> (shift + 8)) == prefix);
            if (inpre) atomicAdd(&hist[(unsigned)((kk[q] >> shift) & 255u)], 1u);
        }
        __syncthreads();
        scan[tid] = hist[tid];
        __syncthreads();
        for (int off = 1; off < 256; off <<= 1) {
            unsigned v = scan[tid] + ((tid + off < 256) ? scan[tid + off] : 0u);
            __syncthreads();
            scan[tid] = v;
            __syncthreads();
        }
        {
            unsigned ge = (unsigned)nA + scan[tid];
            unsigned gt = (unsigned)nA + ((tid < 255) ? scan[tid + 1] : 0u);
            if (ge >= 128u && gt < 128u) {
                sh_B = tid; sh_nA = (int)gt; sh_cnt = (int)hist[tid];
            }
        }
        __syncthreads();
        prefix = (prefix << 8) | (unsigned)sh_B;
        nA = sh_nA;
        if (nA + sh_cnt <= 511 || shift == 0) break;
        shift -= 8;
        __syncthreads();
    }

    // compact survivors (count = nA + cnt <= 511), pad with 0-keys
    list[tid] = 0ull; list[tid + 256] = 0ull;
    if (tid == 0) sh_num = 0;
    __syncthreads();
    #pragma unroll
    for (int q = 0; q < 16; ++q) {
        if ((kk[q] >> shift) >= prefix) {
            int p = atomicAdd(&sh_num, 1);
            if (p < 512) list[p] = kk[q];
        }
    }
    __syncthreads();

    // bitonic sort 512 ascending
    for (int k = 2; k <= 512; k <<= 1) {
        for (int j = k >> 1; j > 0; j >>= 1) {
            for (int w = tid; w < 512; w += 256) {
                int l = w ^ j;
                if (l > w) {
                    unsigned long long av = list[w], bv = list[l];
                    bool up = ((w & k) == 0);
                    if ((av > bv) == up) { list[w] = bv; list[l] = av; }
                }
            }
            __syncthreads();
        }
    }
    if (tid < K_TOP) {
        unsigned long long key = list[511 - tid];   // rank tid (descending)
        const size_t ob = ((size_t)sig * NBANDS + band) * K_TOP + tid;
        topv[ob] = decf((unsigned)(key >> 32));
        topi[ob] = 4095 - (int)(key & 0xFFFFFFFFu);
    }
}

// ---------------------------------------------------------------------------
// K5: loss partial sums (proven r4)
__global__ __launch_bounds__(256) void k_loss(
    const float* __restrict__ topv, const int* __restrict__ topi,
    const __hip_bfloat16* __restrict__ PT, const __hip_bfloat16* __restrict__ PF,
    float* __restrict__ accum)
{
    const int tid = threadIdx.x;
    const int band = blockIdx.x, b = blockIdx.y;
    const size_t bt = ((size_t)b * NBANDS + band) * K_TOP;
    const size_t br = ((size_t)(8 + b) * NBANDS + band) * K_TOP;
    float sum = 0.f;
    for (int k = 0; k < K_TOP; ++k) {
        float vt = topv[bt + k]; int it = topi[bt + k];
        float vr = topv[br + k]; int ir = topi[br + k];
        if (tid < 128) {
            float a = vt * bf2f(PT[(it & 63) * 128 + tid]);
            float c = vr * bf2f(PT[(ir & 63) * 128 + tid]);
            sum += fabsf(a - c);
        } else {
            int j = tid - 128;
            float a = bf2f(PF[(it >> 6) * 128 + j]);
            float c = bf2f(PF[(ir >> 6) * 128 + j]);
            sum += fabsf(a - c);
        }
    }
    __shared__ float red[256];
    red[tid] = sum;
    __syncthreads();
    for (int ofs = 128; ofs > 0; ofs >>= 1) {
        if (tid < ofs) red[tid] += red[tid + ofs];
        __syncthreads();
    }
    if (tid == 0) atomicAdd(accum, red[0]);
}

// ---------------------------------------------------------------------------
// K6: finalize + canary + dual-format store (proven r4)
__global__ __launch_bounds__(256) void k_final(
    const float* __restrict__ C, const float* __restrict__ bands,
    const float* __restrict__ segG, const float* __restrict__ topv,
    const float* __restrict__ accum, unsigned* __restrict__ out)
{
    const int tid = threadIdx.x;
    float s1 = 0.f, s2 = 0.f, s3 = 0.f, s4 = 0.f;
    for (int i = tid; i < 32768; i += 256) s1 += fabsf(C[i]);
    for (int i = tid; i < 512;   i += 256) s2 += fabsf(bands[64 + i]);
    for (int i = tid; i < 4096;  i += 256) s3 += fabsf(segG[i]);
    for (int i = tid; i < 128;   i += 256) s4 += fabsf(topv[i]);
    __shared__ float r1[256], r2[256], r3[256], r4[256];
    r1[tid] = s1; r2[tid] = s2; r3[tid] = s3; r4[tid] = s4;
    __syncthreads();
    for (int ofs = 128; ofs > 0; ofs >>= 1) {
        if (tid < ofs) {
            r1[tid] += r1[tid + ofs]; r2[tid] += r2[tid + ofs];
            r3[tid] += r3[tid + ofs]; r4[tid] += r4[tid + ofs];
        }
        __syncthreads();
    }
    if (tid == 0) {
        float L = accum[0] * (1.0f / 1835008.0f);
        unsigned lu = __float_as_uint(L);
        bool isnanL = ((lu & 0x7F800000u) == 0x7F800000u) && (lu & 0x007FFFFFu);
        float code;
        if      (r1[0] < 1e-3f)  code = 100.f;
        else if (r2[0] < 1e-6f)  code = 200.f;
        else if (r3[0] < 1e-6f)  code = 300.f;
        else if (r4[0] < 1e-9f)  code = 350.f;
        else if (isnanL)         code = 500.f;
        else if (L == 0.f)       code = 400.f;
        else if (fabsf(L) < 1e-6f) code = 600.f;
        else                     code = L;
        unsigned fb = __float_as_uint(code);
        unsigned hb = (fb + 0x7FFFu + ((fb >> 16) & 1u)) >> 16;
        out[0] = (hb << 16) | hb;
    }
}

// ---------------------------------------------------------------------------
extern "C" void kernel_launch(void* const* d_in, const int* in_sizes, int n_in,
                              void* d_out, int out_size, void* d_ws, size_t ws_size,
                              hipStream_t stream)
{
    float* C      = (float*)d_ws;                          // 524288 f
    float* bands  = C + (size_t)NSIG * NBINS * 2;          // 1047552 f
    float* segG   = bands + (size_t)NSIG * BAND_STRIDE;    // 917504 f
    float* topv   = segG + (size_t)NSIG * NBANDS * 64 * 128; // 14336 f
    int*   topi   = (int*)(topv + (size_t)NSIG * NBANDS * K_TOP);
    float* accum  = (float*)(topi + (size_t)NSIG * NBANDS * K_TOP);
    __hip_bfloat16* staged = (__hip_bfloat16*)(accum + 4);  // 16B-aligned
    float* TG = (float*)(staged + ST_TOT);   // T and G alias (T dead before G)
    float* T  = TG;
    float* G  = TG;

    const __hip_bfloat16* xstage = staged + ST_X;
    const __hip_bfloat16* fst    = staged + ST_F;
    const __hip_bfloat16* pts    = staged + ST_PT;
    const __hip_bfloat16* pfs    = staged + ST_PF;

    hipMemsetAsync(d_out, 0x3F, 4, stream);   // no-kernel sentinel

    k_stage  <<<dim3((ST_TOT + 255) / 256 + 1), 256, 0, stream>>>(
                 d_in[0], d_in[1], d_in[2], d_in[3], d_in[4],
                 staged, bands, accum);
    k_fwd1   <<<dim3(16, NSIG),       256, 0, stream>>>(xstage, T);
    k_fwd2   <<<dim3(128, NSIG),      128, 0, stream>>>(T, C);
    k_synthA <<<dim3(254, NSIG),      256, 0, stream>>>(C, G);
    k_synthB <<<dim3(254, NSIG),      256, 0, stream>>>(C, G, bands);
    k_conv   <<<dim3(127, NSIG),      256, 0, stream>>>(bands, fst, segG);
    k_topk   <<<dim3(NBANDS, NSIG),   256, 0, stream>>>(segG, topv, topi);
    k_loss   <<<dim3(NBANDS, 8),      256, 0, stream>>>(topv, topi, pts, pfs, accum);
    k_final  <<<1, 256, 0, stream>>>(C, bands, segG, topv, accum,
                                     (unsigned*)d_out);
}

// Round 10
// 309.543 us; speedup vs baseline: 2.0264x; 1.1064x over previous
//
#include <hip/hip_runtime.h>
#include <hip/hip_bf16.h>

#define N_SAMP    32768
#define NBINS     16384
#define NSIG      16
#define NBANDS    7
#define K_TOP     128
// padded per-signal band buffer: 64 zero-floats of guard before each band
// band i: size s=512<<i, payload offset poff(i) = 64*(i+1) + 512*((1<<i)-1)
#define BAND_STRIDE 65472   // 448 pad + 65024 payload

// staged bf16 layout: [x 16x32768 | filters 4096 | PT 8192 | PF 8192]
#define ST_X   0
#define ST_F   524288
#define ST_PT  528384
#define ST_PF  536576
#define ST_TOT 544864

#define TWO_PI 6.283185307179586f

typedef __attribute__((ext_vector_type(8))) short bf16x8;
typedef __attribute__((ext_vector_type(4))) float f32x4;

__device__ __forceinline__ float bf2f(__hip_bfloat16 v) { return __bfloat162float(v); }

// order-preserving float->uint encoding (monotone)
__device__ __forceinline__ unsigned encf(float f) {
    unsigned u = __float_as_uint(f);
    return (u & 0x80000000u) ? ~u : (u | 0x80000000u);
}
__device__ __forceinline__ float decf(unsigned u) {
    return __uint_as_float((u & 0x80000000u) ? (u ^ 0x80000000u) : ~u);
}

// per-band two-step split constants: M = cnt = (b==0?256:s/4) = M1*M2, L = s/M1
__device__ __forceinline__ int band_M1sh(int b) { return b < 3 ? 4 : (b < 4 ? 5 : 6); }
__device__ __forceinline__ int band_Lsh(int b) {
    return b == 0 ? 5 : (b == 1 ? 6 : (b < 5 ? 7 : (b == 5 ? 8 : 9)));
}
__device__ __forceinline__ int band_M2(int b) {
    return b < 2 ? 16 : (b < 5 ? 32 : (b == 5 ? 64 : 128));
}

// ---------------------------------------------------------------------------
// K_stage: detect dtype per-block + canonicalize inputs to bf16 staging;
// tail block zeroes band guards + accum. (proven r7)
__global__ __launch_bounds__(256) void k_stage(
    const void* __restrict__ t, const void* __restrict__ r,
    const void* __restrict__ f, const void* __restrict__ pt,
    const void* __restrict__ pf,
    __hip_bfloat16* __restrict__ staged,
    float* __restrict__ bands, float* __restrict__ accum)
{
    const int tid = threadIdx.x;
    const int bx  = blockIdx.x;
    if (bx == (ST_TOT + 255) / 256) {
        for (int i = tid; i < NSIG * 448; i += 256) {
            int sig = i / 448, rem = i - sig * 448;
            int g = rem >> 6, j = rem & 63;
            int off = 64 * g + 512 * ((1 << g) - 1);
            bands[(size_t)sig * BAND_STRIDE + off + j] = 0.f;
        }
        if (tid == 0) accum[0] = 0.f;
        return;
    }
    float pv = bf2f(((const __hip_bfloat16*)t)[tid & 63]);
    int bad = (fabsf(pv) > 1e8f) || (pv != pv);
    unsigned long long m = __ballot(bad);
    const int isf32 = (m != 0ull);
    const int id = bx * 256 + tid;
    if (id >= ST_TOT) return;
    const void* src; int idx;
    if (id < 262144)      { src = t;  idx = id; }
    else if (id < ST_F)   { src = r;  idx = id - 262144; }
    else if (id < ST_PT)  { src = f;  idx = id - ST_F; }
    else if (id < ST_PF)  { src = pt; idx = id - ST_PT; }
    else                  { src = pf; idx = id - ST_PF; }
    float v = isf32 ? ((const float*)src)[idx]
                    : bf2f(((const __hip_bfloat16*)src)[idx]);
    staged[id] = __float2bfloat16(v);
}

// ---------------------------------------------------------------------------
// Forward rfft via four-step: N = 128 x 256 (proven r5/r8)
__global__ __launch_bounds__(256) void k_fwd1(
    const __hip_bfloat16* __restrict__ xstage, float* __restrict__ T)
{
    const int n2  = threadIdx.x;
    const int sig = blockIdx.y;
    const int k1b = blockIdx.x * 8;           // 8 k1 per block
    const __hip_bfloat16* x = xstage + (size_t)sig * N_SAMP;
    __shared__ float ct[128], st[128];
    if (n2 < 128) {
        float sv, cv;
        sincosf(TWO_PI * (float)n2 * (1.f / 128.f), &sv, &cv);
        ct[n2] = cv; st[n2] = sv;
    }
    __syncthreads();
    float ar[8], ai[8];
    #pragma unroll
    for (int q = 0; q < 8; ++q) { ar[q] = 0.f; ai[q] = 0.f; }
    for (int n1 = 0; n1 < 128; ++n1) {
        float xv = bf2f(x[n1 * 256 + n2]);
        #pragma unroll
        for (int q = 0; q < 8; ++q) {
            int t = (n1 * (k1b + q)) & 127;   // W128^{n1 k1} = (ct, -st)
            ar[q] = fmaf(xv,  ct[t], ar[q]);
            ai[q] = fmaf(xv, -st[t], ai[q]);
        }
    }
    float2* To = (float2*)T + (size_t)sig * 128 * 256;
    #pragma unroll
    for (int q = 0; q < 8; ++q) {
        int k1 = k1b + q;
        float sv, cv;                          // e^{-i th} = (cv, -sv)
        sincosf((TWO_PI / 32768.f) * (float)(n2 * k1), &sv, &cv);
        float Tr = ar[q] * cv + ai[q] * sv;
        float Ti = ai[q] * cv - ar[q] * sv;
        To[(size_t)k1 * 256 + n2] = make_float2(Tr, Ti);
    }
}

// Step2 with 4 independent rotation chains (break serial dependency)
__global__ __launch_bounds__(128) void k_fwd2(
    const float* __restrict__ T, float* __restrict__ C)
{
    const int k2  = threadIdx.x;              // < 128
    const int k1  = blockIdx.x;
    const int sig = blockIdx.y;
    __shared__ float2 Ts[256];
    const float2* Tin = (const float2*)T + ((size_t)sig * 128 + k1) * 256;
    for (int i = k2; i < 256; i += 128) Ts[i] = Tin[i];
    __syncthreads();
    float er[4], ei[4];
    #pragma unroll
    for (int c = 0; c < 4; ++c) {
        float sv, cv;                          // e^{-2pi i (c k2 mod 256)/256}
        sincosf(-TWO_PI * (float)((c * k2) & 255) * (1.f / 256.f), &sv, &cv);
        er[c] = cv; ei[c] = sv;
    }
    float s4, c4;                              // step by 4: e^{-2pi i 4k2/256}
    sincosf(-TWO_PI * (float)((4 * k2) & 255) * (1.f / 256.f), &s4, &c4);
    float Xr[4] = {0.f,0.f,0.f,0.f}, Xi[4] = {0.f,0.f,0.f,0.f};
    for (int n2 = 0; n2 < 256; n2 += 4) {
        #pragma unroll
        for (int c = 0; c < 4; ++c) {
            float2 t = Ts[n2 + c];
            Xr[c] += t.x * er[c] - t.y * ei[c];
            Xi[c] += t.x * ei[c] + t.y * er[c];
            float nr = er[c] * c4 - ei[c] * s4;
            ei[c]    = er[c] * s4 + ei[c] * c4;
            er[c] = nr;
        }
    }
    const float inv = 5.5242717280199030e-3f;   // 1/sqrt(32768)
    float xr = (Xr[0] + Xr[1]) + (Xr[2] + Xr[3]);
    float xi = (Xi[0] + Xi[1]) + (Xi[2] + Xi[3]);
    float2* Co = (float2*)C + (size_t)sig * NBINS;
    Co[k1 + 128 * k2] = make_float2(xr * inv, xi * inv);
}

// ---------------------------------------------------------------------------
// Band synthesis two-step; 4 independent rotation chains; band-6 blocks first
__global__ __launch_bounds__(256) void k_synthA(
    const float* __restrict__ C, float* __restrict__ G)
{
    const int tid = threadIdx.x;
    const int sig = blockIdx.y;
    int r = 253 - blockIdx.x;           // long (band-6) blocks dispatch first
    int band = 0;
    while (r >= (2 << band)) { r -= (2 << band); ++band; }
    const int s    = 512 << band;
    const int idx  = r * 256 + tid;
    const int m1sh = band_M1sh(band);
    const int lsh  = band_Lsh(band);
    const int M2   = band_M2(band);
    const int L    = 1 << lsh;
    const int a    = (band == 0) ? 0 : (128 << band);
    const int j1   = idx >> lsh;
    const int m    = idx & (L - 1);
    const float2* D = (const float2*)C + (size_t)sig * NBINS + a;
    float er[4], ei[4];
    #pragma unroll
    for (int c = 0; c < 4; ++c) {       // e^{+2pi i (c m mod L)/L}
        float sv, cv;
        sincosf(TWO_PI * (float)((c * m) & (L - 1)) / (float)L, &sv, &cv);
        er[c] = cv; ei[c] = sv;
    }
    float s4, c4;                       // step by 4: e^{+2pi i (4m mod L)/L}
    sincosf(TWO_PI * (float)((4 * m) & (L - 1)) / (float)L, &s4, &c4);
    float gr[4] = {0.f,0.f,0.f,0.f}, gi[4] = {0.f,0.f,0.f,0.f};
    for (int j2 = 0; j2 < M2; j2 += 4) {
        #pragma unroll
        for (int c = 0; c < 4; ++c) {
            float2 d = D[j1 + ((j2 + c) << m1sh)];
            gr[c] += d.x * er[c] - d.y * ei[c];
            gi[c] += d.x * ei[c] + d.y * er[c];
            float nr = er[c] * c4 - ei[c] * s4;
            ei[c]    = er[c] * s4 + ei[c] * c4;
            er[c] = nr;
        }
    }
    const float sc = 2.f * rsqrtf((float)s);
    float grs = (gr[0] + gr[1]) + (gr[2] + gr[3]);
    float gis = (gi[0] + gi[1]) + (gi[2] + gi[3]);
    float2* Go = (float2*)G + (size_t)sig * 65024 + 512 * ((1 << band) - 1);
    Go[idx] = make_float2(grs * sc, gis * sc);
}

__global__ __launch_bounds__(256) void k_synthB(
    const float* __restrict__ C, const float* __restrict__ G,
    float* __restrict__ bands)
{
    const int tid = threadIdx.x;
    const int sig = blockIdx.y;
    int r = 253 - blockIdx.x;           // long (band-6) blocks dispatch first
    int band = 0;
    while (r >= (2 << band)) { r -= (2 << band); ++band; }
    const int s    = 512 << band;
    const int n    = r * 256 + tid;
    const int M1   = 1 << band_M1sh(band);
    const int lsh  = band_Lsh(band);
    const int m    = n & ((1 << lsh) - 1);
    const float2* Gi = (const float2*)G + (size_t)sig * 65024 + 512 * ((1 << band) - 1);
    float er[4], ei[4];
    #pragma unroll
    for (int c = 0; c < 4; ++c) {       // e^{+2pi i (c n mod s)/s}
        float sv, cv;
        sincosf(TWO_PI * (float)((c * n) & (s - 1)) / (float)s, &sv, &cv);
        er[c] = cv; ei[c] = sv;
    }
    float s4, c4;                       // step by 4: e^{+2pi i (4n mod s)/s}
    sincosf(TWO_PI * (float)((4 * n) & (s - 1)) / (float)s, &s4, &c4);
    float zr[4] = {0.f,0.f,0.f,0.f}, zi[4] = {0.f,0.f,0.f,0.f};
    for (int j1 = 0; j1 < M1; j1 += 4) {
        #pragma unroll
        for (int c = 0; c < 4; ++c) {
            float2 g = Gi[((j1 + c) << lsh) + m];
            zr[c] += g.x * er[c] - g.y * ei[c];
            zi[c] += g.x * ei[c] + g.y * er[c];
            float nr = er[c] * c4 - ei[c] * s4;
            ei[c]    = er[c] * s4 + ei[c] * c4;
            er[c] = nr;
        }
    }
    float zrs = (zr[0] + zr[1]) + (zr[2] + zr[3]);
    float zis = (zi[0] + zi[1]) + (zi[2] + zi[3]);
    float val;
    if (band == 0) {
        val = zrs - C[(size_t)sig * NBINS * 2] * 0.04419417382415922f; // 1/sqrt(512)
    } else {
        switch (n & 3) {                // Re(i^n * z)
            case 0:  val =  zrs; break;
            case 1:  val = -zis; break;
            case 2:  val = -zrs; break;
            default: val =  zis; break;
        }
    }
    const int poff = 64 * (band + 1) + 512 * ((1 << band) - 1);
    bands[(size_t)sig * BAND_STRIDE + poff + n] = val;
}

// ---------------------------------------------------------------------------
// K3: MFMA conv + fused segment-max pooling (proven r8, bit-exact)
__global__ __launch_bounds__(256) void k_conv(
    const float* __restrict__ bands,
    const __hip_bfloat16* __restrict__ filters,
    float* __restrict__ segG)
{
    const int tid  = threadIdx.x;
    const int sig  = blockIdx.y;
    const int c    = blockIdx.x;               // 0..126
    const int band = 31 - __clz(c + 1);        // chunks per band = 1<<band
    const int cidx = c + 1 - (1 << band);
    const int poff = 64 * (band + 1) + 512 * ((1 << band) - 1);
    const float* bp = bands + (size_t)sig * BAND_STRIDE + poff + cidx * 512;

    __shared__ __align__(16) __hip_bfloat16 xr[8][584]; // 8 shifted reversed copies
    __shared__ float segP[64 * 4];                      // band-6 wave partials

    for (int i = tid; i < 576; i += 256) {
        __hip_bfloat16 b = __float2bfloat16(bp[511 - i]);
        #pragma unroll
        for (int p = 0; p < 8; ++p) {
            int idx = i - p;
            if (idx >= 0) xr[p][idx] = b;
        }
    }
    __syncthreads();

    const int tl   = tid & 15;
    const int quad = (tid >> 4) & 3;
    const int wave = tid >> 6;

    bf16x8 bf0[4], bf1[4];
    #pragma unroll
    for (int ft = 0; ft < 4; ++ft) {
        const __hip_bfloat16* fp = filters + ((ft * 16 + tl) * 64 + quad * 8);
        bf0[ft] = *(const bf16x8*)(fp);
        bf1[ft] = *(const bf16x8*)(fp + 32);
    }

    int s0 = 511 - wave * 128 - tl + 8 * quad;
    const __hip_bfloat16* xp = &xr[0][0] + (s0 & 7) * 584 + (s0 & ~7);

    const int spc = 512 >> (2 + band);          // segs per chunk
    float* segO = segG + (size_t)(sig * NBANDS + band) * 64 * 128 + cidx * spc;

    const float NEG = -3.4e38f;
    float run0 = NEG, run1 = NEG, run2 = NEG, run3 = NEG;
    const int per = (band >= 2) ? (1 << (band - 2)) : 1;   // tiles per segment

    for (int it = 0; it < 8; ++it) {
        const int t0 = wave * 128 + it * 16;
        bf16x8 a0 = *(const bf16x8*)(xp);
        bf16x8 a1 = *(const bf16x8*)(xp + 32);
        xp -= 16;
        f32x4 ac0 = {0.f,0.f,0.f,0.f}, ac1 = ac0, ac2 = ac0, ac3 = ac0;
        ac0 = __builtin_amdgcn_mfma_f32_16x16x32_bf16(a0, bf0[0], ac0, 0, 0, 0);
        ac0 = __builtin_amdgcn_mfma_f32_16x16x32_bf16(a1, bf1[0], ac0, 0, 0, 0);
        ac1 = __builtin_amdgcn_mfma_f32_16x16x32_bf16(a0, bf0[1], ac1, 0, 0, 0);
        ac1 = __builtin_amdgcn_mfma_f32_16x16x32_bf16(a1, bf1[1], ac1, 0, 0, 0);
        ac2 = __builtin_amdgcn_mfma_f32_16x16x32_bf16(a0, bf0[2], ac2, 0, 0, 0);
        ac2 = __builtin_amdgcn_mfma_f32_16x16x32_bf16(a1, bf1[2], ac2, 0, 0, 0);
        ac3 = __builtin_amdgcn_mfma_f32_16x16x32_bf16(a0, bf0[3], ac3, 0, 0, 0);
        ac3 = __builtin_amdgcn_mfma_f32_16x16x32_bf16(a1, bf1[3], ac3, 0, 0, 0);
        float m0 = fmaxf(fmaxf(ac0[0], ac0[1]), fmaxf(ac0[2], ac0[3]));
        float m1 = fmaxf(fmaxf(ac1[0], ac1[1]), fmaxf(ac1[2], ac1[3]));
        float m2 = fmaxf(fmaxf(ac2[0], ac2[1]), fmaxf(ac2[2], ac2[3]));
        float m3 = fmaxf(fmaxf(ac3[0], ac3[1]), fmaxf(ac3[2], ac3[3]));
        if (band == 0) {
            int sb = (t0 >> 2) + quad;
            segO[(tl     ) * 128 + sb] = m0;
            segO[(tl + 16) * 128 + sb] = m1;
            segO[(tl + 32) * 128 + sb] = m2;
            segO[(tl + 48) * 128 + sb] = m3;
        } else if (band == 1) {
            m0 = fmaxf(m0, __shfl_xor(m0, 16));
            m1 = fmaxf(m1, __shfl_xor(m1, 16));
            m2 = fmaxf(m2, __shfl_xor(m2, 16));
            m3 = fmaxf(m3, __shfl_xor(m3, 16));
            if ((quad & 1) == 0) {
                int sb = (t0 >> 3) + (quad >> 1);
                segO[(tl     ) * 128 + sb] = m0;
                segO[(tl + 16) * 128 + sb] = m1;
                segO[(tl + 32) * 128 + sb] = m2;
                segO[(tl + 48) * 128 + sb] = m3;
            }
        } else {
            m0 = fmaxf(m0, __shfl_xor(m0, 16)); m0 = fmaxf(m0, __shfl_xor(m0, 32));
            m1 = fmaxf(m1, __shfl_xor(m1, 16)); m1 = fmaxf(m1, __shfl_xor(m1, 32));
            m2 = fmaxf(m2, __shfl_xor(m2, 16)); m2 = fmaxf(m2, __shfl_xor(m2, 32));
            m3 = fmaxf(m3, __shfl_xor(m3, 16)); m3 = fmaxf(m3, __shfl_xor(m3, 32));
            run0 = fmaxf(run0, m0); run1 = fmaxf(run1, m1);
            run2 = fmaxf(run2, m2); run3 = fmaxf(run3, m3);
            if (((it + 1) & (per - 1)) == 0) {
                int sb = t0 >> (2 + band);
                float rv = quad == 0 ? run0 : quad == 1 ? run1
                         : quad == 2 ? run2 : run3;
                segO[(tl + 16 * quad) * 128 + sb] = rv;
                run0 = NEG; run1 = NEG; run2 = NEG; run3 = NEG;
            }
        }
    }
    if (band == 6) {
        float rv = quad == 0 ? run0 : quad == 1 ? run1
                 : quad == 2 ? run2 : run3;
        segP[(tl + 16 * quad) * 4 + wave] = rv;
        __syncthreads();
        if (tid < 128) {
            int f = tid & 63, sg = tid >> 6;
            segO[f * 128 + sg] =
                fmaxf(segP[f * 4 + 2 * sg], segP[f * 4 + 2 * sg + 1]);
        }
    }
}

// ---------------------------------------------------------------------------
// K4: pool + top-128 via radix select + small bitonic sort (proven r9)
__global__ __launch_bounds__(256) void k_topk(
    const float* __restrict__ segG,
    float* __restrict__ topv, int* __restrict__ topi)
{
    const int tid = threadIdx.x;
    const int band = blockIdx.x, sig = blockIdx.y;
    const float* segB = segG + (size_t)(sig * NBANDS + band) * 64 * 128;

    __shared__ unsigned hist[256];
    __shared__ unsigned scan[256];
    __shared__ unsigned long long list[512];
    __shared__ int sh_B, sh_nA, sh_cnt, sh_num;

    unsigned long long kk[16];
    #pragma unroll
    for (int q = 0; q < 16; ++q) {
        int i = q * 256 + tid;
        int f = i >> 6, t = i & 63;
        const float* sg = segB + f * 128;
        float m = fmaxf(sg[2 * t], sg[2 * t + 1]);
        if (t > 0)  m = fmaxf(m, sg[2 * t - 1]);
        if (t < 63) m = fmaxf(m, sg[2 * t + 2]);
        kk[q] = ((unsigned long long)encf(m) << 32) | (unsigned)(4095 - i);
    }

    int shift = 56;
    unsigned long long prefix = 0;
    int nA = 0;
    for (int lev = 0; lev < 8; ++lev) {
        hist[tid] = 0;
        __syncthreads();
        #pragma unroll
        for (int q = 0; q < 16; ++q) {
            bool inpre = (lev == 0) || ((kk[q] >> (shift + 8)) == prefix);
            if (inpre) atomicAdd(&hist[(unsigned)((kk[q] >> shift) & 255u)], 1u);
        }
        __syncthreads();
        scan[tid] = hist[tid];
        __syncthreads();
        for (int off = 1; off < 256; off <<= 1) {
            unsigned v = scan[tid] + ((tid + off < 256) ? scan[tid + off] : 0u);
            __syncthreads();
            scan[tid] = v;
            __syncthreads();
        }
        {
            unsigned ge = (unsigned)nA + scan[tid];
            unsigned gt = (unsigned)nA + ((tid < 255) ? scan[tid + 1] : 0u);
            if (ge >= 128u && gt < 128u) {
                sh_B = tid; sh_nA = (int)gt; sh_cnt = (int)hist[tid];
            }
        }
        __syncthreads();
        prefix = (prefix << 8) | (unsigned)sh_B;
        nA = sh_nA;
        if (nA + sh_cnt <= 511 || shift == 0) break;
        shift -= 8;
        __syncthreads();
    }

    list[tid] = 0ull; list[tid + 256] = 0ull;
    if (tid == 0) sh_num = 0;
    __syncthreads();
    #pragma unroll
    for (int q = 0; q < 16; ++q) {
        if ((kk[q] >> shift) >= prefix) {
            int p = atomicAdd(&sh_num, 1);
            if (p < 512) list[p] = kk[q];
        }
    }
    __syncthreads();

    for (int k = 2; k <= 512; k <<= 1) {
        for (int j = k >> 1; j > 0; j >>= 1) {
            for (int w = tid; w < 512; w += 256) {
                int l = w ^ j;
                if (l > w) {
                    unsigned long long av = list[w], bv = list[l];
                    bool up = ((w & k) == 0);
                    if ((av > bv) == up) { list[w] = bv; list[l] = av; }
                }
            }
            __syncthreads();
        }
    }
    if (tid < K_TOP) {
        unsigned long long key = list[511 - tid];   // rank tid (descending)
        const size_t ob = ((size_t)sig * NBANDS + band) * K_TOP + tid;
        topv[ob] = decf((unsigned)(key >> 32));
        topi[ob] = 4095 - (int)(key & 0xFFFFFFFFu);
    }
}

// ---------------------------------------------------------------------------
// K5: loss partial sums (proven r4)
__global__ __launch_bounds__(256) void k_loss(
    const float* __restrict__ topv, const int* __restrict__ topi,
    const __hip_bfloat16* __restrict__ PT, const __hip_bfloat16* __restrict__ PF,
    float* __restrict__ accum)
{
    const int tid = threadIdx.x;
    const int band = blockIdx.x, b = blockIdx.y;
    const size_t bt = ((size_t)b * NBANDS + band) * K_TOP;
    const size_t br = ((size_t)(8 + b) * NBANDS + band) * K_TOP;
    float sum = 0.f;
    for (int k = 0; k < K_TOP; ++k) {
        float vt = topv[bt + k]; int it = topi[bt + k];
        float vr = topv[br + k]; int ir = topi[br + k];
        if (tid < 128) {
            float a = vt * bf2f(PT[(it & 63) * 128 + tid]);
            float c = vr * bf2f(PT[(ir & 63) * 128 + tid]);
            sum += fabsf(a - c);
        } else {
            int j = tid - 128;
            float a = bf2f(PF[(it >> 6) * 128 + j]);
            float c = bf2f(PF[(ir >> 6) * 128 + j]);
            sum += fabsf(a - c);
        }
    }
    __shared__ float red[256];
    red[tid] = sum;
    __syncthreads();
    for (int ofs = 128; ofs > 0; ofs >>= 1) {
        if (tid < ofs) red[tid] += red[tid + ofs];
        __syncthreads();
    }
    if (tid == 0) atomicAdd(accum, red[0]);
}

// ---------------------------------------------------------------------------
// K6: finalize + canary + dual-format store (proven r4)
__global__ __launch_bounds__(256) void k_final(
    const float* __restrict__ C, const float* __restrict__ bands,
    const float* __restrict__ segG, const float* __restrict__ topv,
    const float* __restrict__ accum, unsigned* __restrict__ out)
{
    const int tid = threadIdx.x;
    float s1 = 0.f, s2 = 0.f, s3 = 0.f, s4 = 0.f;
    for (int i = tid; i < 32768; i += 256) s1 += fabsf(C[i]);
    for (int i = tid; i < 512;   i += 256) s2 += fabsf(bands[64 + i]);
    for (int i = tid; i < 4096;  i += 256) s3 += fabsf(segG[i]);
    for (int i = tid; i < 128;   i += 256) s4 += fabsf(topv[i]);
    __shared__ float r1[256], r2[256], r3[256], r4[256];
    r1[tid] = s1; r2[tid] = s2; r3[tid] = s3; r4[tid] = s4;
    __syncthreads();
    for (int ofs = 128; ofs > 0; ofs >>= 1) {
        if (tid < ofs) {
            r1[tid] += r1[tid + ofs]; r2[tid] += r2[tid + ofs];
            r3[tid] += r3[tid + ofs]; r4[tid] += r4[tid + ofs];
        }
        __syncthreads();
    }
    if (tid == 0) {
        float L = accum[0] * (1.0f / 1835008.0f);
        unsigned lu = __float_as_uint(L);
        bool isnanL = ((lu & 0x7F800000u) == 0x7F800000u) && (lu & 0x007FFFFFu);
        float code;
        if      (r1[0] < 1e-3f)  code = 100.f;
        else if (r2[0] < 1e-6f)  code = 200.f;
        else if (r3[0] < 1e-6f)  code = 300.f;
        else if (r4[0] < 1e-9f)  code = 350.f;
        else if (isnanL)         code = 500.f;
        else if (L == 0.f)       code = 400.f;
        else if (fabsf(L) < 1e-6f) code = 600.f;
        else                     code = L;
        unsigned fb = __float_as_uint(code);
        unsigned hb = (fb + 0x7FFFu + ((fb >> 16) & 1u)) >> 16;
        out[0] = (hb << 16) | hb;
    }
}

// ---------------------------------------------------------------------------
extern "C" void kernel_launch(void* const* d_in, const int* in_sizes, int n_in,
                              void* d_out, int out_size, void* d_ws, size_t ws_size,
                              hipStream_t stream)
{
    float* C      = (float*)d_ws;                          // 524288 f
    float* bands  = C + (size_t)NSIG * NBINS * 2;          // 1047552 f
    float* segG   = bands + (size_t)NSIG * BAND_STRIDE;    // 917504 f
    float* topv   = segG + (size_t)NSIG * NBANDS * 64 * 128; // 14336 f
    int*   topi   = (int*)(topv + (size_t)NSIG * NBANDS * K_TOP);
    float* accum  = (float*)(topi + (size_t)NSIG * NBANDS * K_TOP);
    __hip_bfloat16* staged = (__hip_bfloat16*)(accum + 4);  // 16B-aligned
    float* TG = (float*)(staged + ST_TOT);   // T and G alias (T dead before G)
    float* T  = TG;
    float* G  = TG;

    const __hip_bfloat16* xstage = staged + ST_X;
    const __hip_bfloat16* fst    = staged + ST_F;
    const __hip_bfloat16* pts    = staged + ST_PT;
    const __hip_bfloat16* pfs    = staged + ST_PF;

    hipMemsetAsync(d_out, 0x3F, 4, stream);   // no-kernel sentinel

    k_stage  <<<dim3((ST_TOT + 255) / 256 + 1), 256, 0, stream>>>(
                 d_in[0], d_in[1], d_in[2], d_in[3], d_in[4],
                 staged, bands, accum);
    k_fwd1   <<<dim3(16, NSIG),       256, 0, stream>>>(xstage, T);
    k_fwd2   <<<dim3(128, NSIG),      128, 0, stream>>>(T, C);
    k_synthA <<<dim3(254, NSIG),      256, 0, stream>>>(C, G);
    k_synthB <<<dim3(254, NSIG),      256, 0, stream>>>(C, G, bands);
    k_conv   <<<dim3(127, NSIG),      256, 0, stream>>>(bands, fst, segG);
    k_topk   <<<dim3(NBANDS, NSIG),   256, 0, stream>>>(segG, topv, topi);
    k_loss   <<<dim3(NBANDS, 8),      256, 0, stream>>>(topv, topi, pts, pfs, accum);
    k_final  <<<1, 256, 0, stream>>>(C, bands, segG, topv, accum,
                                     (unsigned*)d_out);
}

// Round 11
// 254.365 us; speedup vs baseline: 2.4659x; 1.2169x over previous
//
#include <hip/hip_runtime.h>
#include <hip/hip_bf16.h>

#define N_SAMP    32768
#define NBINS     16384
#define NSIG      16
#define NBANDS    7
#define K_TOP     128
// padded per-signal band buffer: 64 zero-floats of guard before each band
// band i: size s=512<<i, payload offset poff(i) = 64*(i+1) + 512*((1<<i)-1)
#define BAND_STRIDE 65472   // 448 pad + 65024 payload

// staged bf16 layout: [x 16x32768 | filters 4096 | PT 8192 | PF 8192]
#define ST_X   0
#define ST_F   524288
#define ST_PT  528384
#define ST_PF  536576
#define ST_TOT 544864

#define TWO_PI 6.283185307179586f

typedef __attribute__((ext_vector_type(8))) short bf16x8;
typedef __attribute__((ext_vector_type(4))) float f32x4;

__device__ __forceinline__ float bf2f(__hip_bfloat16 v) { return __bfloat162float(v); }

// order-preserving float->uint encoding (monotone)
__device__ __forceinline__ unsigned encf(float f) {
    unsigned u = __float_as_uint(f);
    return (u & 0x80000000u) ? ~u : (u | 0x80000000u);
}
__device__ __forceinline__ float decf(unsigned u) {
    return __uint_as_float((u & 0x80000000u) ? (u ^ 0x80000000u) : ~u);
}

// per-band two-step split constants: M = cnt = (b==0?256:s/4) = M1*M2, L = s/M1
__device__ __forceinline__ int band_M1sh(int b) { return b < 3 ? 4 : (b < 4 ? 5 : 6); }
__device__ __forceinline__ int band_Lsh(int b) {
    return b == 0 ? 5 : (b == 1 ? 6 : (b < 5 ? 7 : (b == 5 ? 8 : 9)));
}
__device__ __forceinline__ int band_M2sh(int b) {
    return b < 2 ? 4 : (b < 5 ? 5 : (b == 5 ? 6 : 7));
}

// ---------------------------------------------------------------------------
// K_stage: detect dtype per-block + canonicalize inputs to bf16 staging;
// tail block zeroes band guards + accum. (proven r7)
__global__ __launch_bounds__(256) void k_stage(
    const void* __restrict__ t, const void* __restrict__ r,
    const void* __restrict__ f, const void* __restrict__ pt,
    const void* __restrict__ pf,
    __hip_bfloat16* __restrict__ staged,
    float* __restrict__ bands, float* __restrict__ accum)
{
    const int tid = threadIdx.x;
    const int bx  = blockIdx.x;
    if (bx == (ST_TOT + 255) / 256) {
        for (int i = tid; i < NSIG * 448; i += 256) {
            int sig = i / 448, rem = i - sig * 448;
            int g = rem >> 6, j = rem & 63;
            int off = 64 * g + 512 * ((1 << g) - 1);
            bands[(size_t)sig * BAND_STRIDE + off + j] = 0.f;
        }
        if (tid == 0) accum[0] = 0.f;
        return;
    }
    float pv = bf2f(((const __hip_bfloat16*)t)[tid & 63]);
    int bad = (fabsf(pv) > 1e8f) || (pv != pv);
    unsigned long long m = __ballot(bad);
    const int isf32 = (m != 0ull);
    const int id = bx * 256 + tid;
    if (id >= ST_TOT) return;
    const void* src; int idx;
    if (id < 262144)      { src = t;  idx = id; }
    else if (id < ST_F)   { src = r;  idx = id - 262144; }
    else if (id < ST_PT)  { src = f;  idx = id - ST_F; }
    else if (id < ST_PF)  { src = pt; idx = id - ST_PT; }
    else                  { src = pf; idx = id - ST_PF; }
    float v = isf32 ? ((const float*)src)[idx]
                    : bf2f(((const __hip_bfloat16*)src)[idx]);
    staged[id] = __float2bfloat16(v);
}

// ---------------------------------------------------------------------------
// Forward rfft via four-step: N = 128 x 256 (proven r5/r8)
__global__ __launch_bounds__(256) void k_fwd1(
    const __hip_bfloat16* __restrict__ xstage, float* __restrict__ T)
{
    const int n2  = threadIdx.x;
    const int sig = blockIdx.y;
    const int k1b = blockIdx.x * 8;           // 8 k1 per block
    const __hip_bfloat16* x = xstage + (size_t)sig * N_SAMP;
    __shared__ float ct[128], st[128];
    if (n2 < 128) {
        float sv, cv;
        sincosf(TWO_PI * (float)n2 * (1.f / 128.f), &sv, &cv);
        ct[n2] = cv; st[n2] = sv;
    }
    __syncthreads();
    float ar[8], ai[8];
    #pragma unroll
    for (int q = 0; q < 8; ++q) { ar[q] = 0.f; ai[q] = 0.f; }
    for (int n1 = 0; n1 < 128; ++n1) {
        float xv = bf2f(x[n1 * 256 + n2]);
        #pragma unroll
        for (int q = 0; q < 8; ++q) {
            int t = (n1 * (k1b + q)) & 127;   // W128^{n1 k1} = (ct, -st)
            ar[q] = fmaf(xv,  ct[t], ar[q]);
            ai[q] = fmaf(xv, -st[t], ai[q]);
        }
    }
    float2* To = (float2*)T + (size_t)sig * 128 * 256;
    #pragma unroll
    for (int q = 0; q < 8; ++q) {
        int k1 = k1b + q;
        float sv, cv;                          // e^{-i th} = (cv, -sv)
        sincosf((TWO_PI / 32768.f) * (float)(n2 * k1), &sv, &cv);
        float Tr = ar[q] * cv + ai[q] * sv;
        float Ti = ai[q] * cv - ar[q] * sv;
        To[(size_t)k1 * 256 + n2] = make_float2(Tr, Ti);
    }
}

// Step2 with 4 independent rotation chains (proven r10)
__global__ __launch_bounds__(128) void k_fwd2(
    const float* __restrict__ T, float* __restrict__ C)
{
    const int k2  = threadIdx.x;              // < 128
    const int k1  = blockIdx.x;
    const int sig = blockIdx.y;
    __shared__ float2 Ts[256];
    const float2* Tin = (const float2*)T + ((size_t)sig * 128 + k1) * 256;
    for (int i = k2; i < 256; i += 128) Ts[i] = Tin[i];
    __syncthreads();
    float er[4], ei[4];
    #pragma unroll
    for (int c = 0; c < 4; ++c) {
        float sv, cv;                          // e^{-2pi i (c k2 mod 256)/256}
        sincosf(-TWO_PI * (float)((c * k2) & 255) * (1.f / 256.f), &sv, &cv);
        er[c] = cv; ei[c] = sv;
    }
    float s4, c4;                              // step by 4: e^{-2pi i 4k2/256}
    sincosf(-TWO_PI * (float)((4 * k2) & 255) * (1.f / 256.f), &s4, &c4);
    float Xr[4] = {0.f,0.f,0.f,0.f}, Xi[4] = {0.f,0.f,0.f,0.f};
    for (int n2 = 0; n2 < 256; n2 += 4) {
        #pragma unroll
        for (int c = 0; c < 4; ++c) {
            float2 t = Ts[n2 + c];
            Xr[c] += t.x * er[c] - t.y * ei[c];
            Xi[c] += t.x * ei[c] + t.y * er[c];
            float nr = er[c] * c4 - ei[c] * s4;
            ei[c]    = er[c] * s4 + ei[c] * c4;
            er[c] = nr;
        }
    }
    const float inv = 5.5242717280199030e-3f;   // 1/sqrt(32768)
    float xr = (Xr[0] + Xr[1]) + (Xr[2] + Xr[3]);
    float xi = (Xi[0] + Xi[1]) + (Xi[2] + Xi[3]);
    float2* Co = (float2*)C + (size_t)sig * NBINS;
    Co[k1 + 128 * k2] = make_float2(xr * inv, xi * inv);
}

// ---------------------------------------------------------------------------
// Band synthesis — QUARTER-BAND DECIMATION. Output idx = j1*L + m + q*(L/4):
// twiddle factors as e^{2pi i j2 m/L} * i^{j2 q}. One rotation chain feeds 4
// outputs via sign/swap adds: 4 ops/cMAC (was 8) + 4x fewer loads.
// 64 blocks/sig: block 0=band0(128thr),1=b1,2-3=b2,...,32-63=b6 (b6 first).
__global__ __launch_bounds__(256) void k_synthA(
    const float* __restrict__ C, float* __restrict__ G)
{
    const int tid = threadIdx.x;
    const int sig = blockIdx.y;
    const int bix = 63 - blockIdx.x;            // band-6 blocks dispatch first
    const int band = (bix == 0) ? 0 : (32 - __clz(bix));
    const int lbx  = (band == 0) ? 0 : (bix - (1 << (band - 1)));
    const int s    = 512 << band;
    const int m1sh = band_M1sh(band);
    const int lsh  = band_Lsh(band);
    const int m2sh = band_M2sh(band);
    const int M2   = 1 << m2sh;
    const int L    = 1 << lsh;
    const int L4   = L >> 2;
    const int a    = (band == 0) ? 0 : (128 << band);
    const int tix  = lbx * 256 + tid;
    // stage needed D bins into LDS: Ds[(j1-j1lo)*M2 + j2]
    const int j1lo = (lbx * 256) >> (lsh - 2);
    int j1cnt = 256 >> (lsh - 2);
    if (j1cnt > (1 << m1sh)) j1cnt = 1 << m1sh;
    __shared__ float2 Ds[256];
    const float2* D = (const float2*)C + (size_t)sig * NBINS + a;
    for (int i = tid; i < (j1cnt << m2sh); i += 256) {
        int j1o = i >> m2sh, j2 = i & (M2 - 1);
        Ds[i] = D[(j1lo + j1o) + (j2 << m1sh)];
    }
    __syncthreads();
    if (tix >= (128 << band)) return;           // s/4 threads per band
    const int j1o = (tix >> (lsh - 2)) - j1lo;
    const int m   = tix & (L4 - 1);
    const float2* Dj = Ds + (j1o << m2sh);
    // 2 chains (j2 parity); twiddle e^{+2pi i j2 m/L}, step e^{+2pi i 2m/L}
    float e0r = 1.f, e0i = 0.f, e1r, e1i, sr, si;
    sincosf(TWO_PI * (float)m / (float)L, &e1i, &e1r);
    sincosf(TWO_PI * (float)(2 * m) / (float)L, &si, &sr);
    float ar[4] = {0.f,0.f,0.f,0.f}, ai[4] = {0.f,0.f,0.f,0.f};
    for (int j2 = 0; j2 < M2; j2 += 4) {
        {   // p = 0 (chain 0): factor 1 for all q
            float2 d = Dj[j2];
            float tr = d.x * e0r - d.y * e0i, ti = d.x * e0i + d.y * e0r;
            ar[0] += tr; ai[0] += ti; ar[1] += tr; ai[1] += ti;
            ar[2] += tr; ai[2] += ti; ar[3] += tr; ai[3] += ti;
            float nr = e0r * sr - e0i * si; e0i = e0r * si + e0i * sr; e0r = nr;
        }
        {   // p = 1 (chain 1): factors 1, i, -1, -i
            float2 d = Dj[j2 + 1];
            float tr = d.x * e1r - d.y * e1i, ti = d.x * e1i + d.y * e1r;
            ar[0] += tr; ai[0] += ti;
            ar[1] -= ti; ai[1] += tr;
            ar[2] -= tr; ai[2] -= ti;
            ar[3] += ti; ai[3] -= tr;
            float nr = e1r * sr - e1i * si; e1i = e1r * si + e1i * sr; e1r = nr;
        }
        {   // p = 2 (chain 0): factors 1, -1, 1, -1
            float2 d = Dj[j2 + 2];
            float tr = d.x * e0r - d.y * e0i, ti = d.x * e0i + d.y * e0r;
            ar[0] += tr; ai[0] += ti;
            ar[1] -= tr; ai[1] -= ti;
            ar[2] += tr; ai[2] += ti;
            ar[3] -= tr; ai[3] -= ti;
            float nr = e0r * sr - e0i * si; e0i = e0r * si + e0i * sr; e0r = nr;
        }
        {   // p = 3 (chain 1): factors 1, -i, -1, i
            float2 d = Dj[j2 + 3];
            float tr = d.x * e1r - d.y * e1i, ti = d.x * e1i + d.y * e1r;
            ar[0] += tr; ai[0] += ti;
            ar[1] += ti; ai[1] -= tr;
            ar[2] -= tr; ai[2] -= ti;
            ar[3] -= ti; ai[3] += tr;
            float nr = e1r * sr - e1i * si; e1i = e1r * si + e1i * sr; e1r = nr;
        }
    }
    const float sc = 2.f * rsqrtf((float)s);
    float2* Go = (float2*)G + (size_t)sig * 65024 + 512 * ((1 << band) - 1);
    const int base = ((tix >> (lsh - 2)) << lsh) + m;   // j1*L + m
    #pragma unroll
    for (int q = 0; q < 4; ++q)
        Go[base + q * L4] = make_float2(ar[q] * sc, ai[q] * sc);
}

// synthB with the same i^q decimation: outputs n_q = n + q*s/4 share m and
// the i^n phase (s/4 = 0 mod 4). Factor i^{j1 q} -> sign/swap adds.
__global__ __launch_bounds__(256) void k_synthB(
    const float* __restrict__ C, const float* __restrict__ G,
    float* __restrict__ bands)
{
    const int tid = threadIdx.x;
    const int sig = blockIdx.y;
    const int bix = 63 - blockIdx.x;            // band-6 blocks dispatch first
    const int band = (bix == 0) ? 0 : (32 - __clz(bix));
    const int lbx  = (band == 0) ? 0 : (bix - (1 << (band - 1)));
    const int s    = 512 << band;
    const int M1   = 1 << band_M1sh(band);
    const int lsh  = band_Lsh(band);
    const int n    = lbx * 256 + tid;           // [0, s/4)
    const int s4   = s >> 2;
    if (n >= s4) return;
    const int m    = n & ((1 << lsh) - 1);
    const float2* Gi = (const float2*)G + (size_t)sig * 65024 + 512 * ((1 << band) - 1);
    float e0r = 1.f, e0i = 0.f, e1r, e1i, sr, si;
    sincosf(TWO_PI * (float)n / (float)s, &e1i, &e1r);
    sincosf(TWO_PI * (float)(2 * n) / (float)s, &si, &sr);
    float zr[4] = {0.f,0.f,0.f,0.f}, zi[4] = {0.f,0.f,0.f,0.f};
    for (int j1 = 0; j1 < M1; j1 += 4) {
        {   // p = 0 (chain 0)
            float2 g = Gi[((j1 + 0) << lsh) + m];
            float tr = g.x * e0r - g.y * e0i, ti = g.x * e0i + g.y * e0r;
            zr[0] += tr; zi[0] += ti; zr[1] += tr; zi[1] += ti;
            zr[2] += tr; zi[2] += ti; zr[3] += tr; zi[3] += ti;
            float nr = e0r * sr - e0i * si; e0i = e0r * si + e0i * sr; e0r = nr;
        }
        {   // p = 1 (chain 1): 1, i, -1, -i
            float2 g = Gi[((j1 + 1) << lsh) + m];
            float tr = g.x * e1r - g.y * e1i, ti = g.x * e1i + g.y * e1r;
            zr[0] += tr; zi[0] += ti;
            zr[1] -= ti; zi[1] += tr;
            zr[2] -= tr; zi[2] -= ti;
            zr[3] += ti; zi[3] -= tr;
            float nr = e1r * sr - e1i * si; e1i = e1r * si + e1i * sr; e1r = nr;
        }
        {   // p = 2 (chain 0): 1, -1, 1, -1
            float2 g = Gi[((j1 + 2) << lsh) + m];
            float tr = g.x * e0r - g.y * e0i, ti = g.x * e0i + g.y * e0r;
            zr[0] += tr; zi[0] += ti;
            zr[1] -= tr; zi[1] -= ti;
            zr[2] += tr; zi[2] += ti;
            zr[3] -= tr; zi[3] -= ti;
            float nr = e0r * sr - e0i * si; e0i = e0r * si + e0i * sr; e0r = nr;
        }
        {   // p = 3 (chain 1): 1, -i, -1, i
            float2 g = Gi[((j1 + 3) << lsh) + m];
            float tr = g.x * e1r - g.y * e1i, ti = g.x * e1i + g.y * e1r;
            zr[0] += tr; zi[0] += ti;
            zr[1] += ti; zi[1] -= tr;
            zr[2] -= tr; zi[2] -= ti;
            zr[3] -= ti; zi[3] += tr;
            float nr = e1r * sr - e1i * si; e1i = e1r * si + e1i * sr; e1r = nr;
        }
    }
    const int poff = 64 * (band + 1) + 512 * ((1 << band) - 1);
    float* bo = bands + (size_t)sig * BAND_STRIDE + poff;
    if (band == 0) {
        const float dc = C[(size_t)sig * NBINS * 2] * 0.04419417382415922f; // /sqrt512
        #pragma unroll
        for (int q = 0; q < 4; ++q) bo[n + q * s4] = zr[q] - dc;
    } else {
        #pragma unroll
        for (int q = 0; q < 4; ++q) {
            float val;
            switch (n & 3) {                // Re(i^n * z), same phase for all q
                case 0:  val =  zr[q]; break;
                case 1:  val = -zi[q]; break;
                case 2:  val = -zr[q]; break;
                default: val =  zi[q]; break;
            }
            bo[n + q * s4] = val;
        }
    }
}

// ---------------------------------------------------------------------------
// K3: MFMA conv + fused segment-max pooling (proven r8, bit-exact)
__global__ __launch_bounds__(256) void k_conv(
    const float* __restrict__ bands,
    const __hip_bfloat16* __restrict__ filters,
    float* __restrict__ segG)
{
    const int tid  = threadIdx.x;
    const int sig  = blockIdx.y;
    const int c    = blockIdx.x;               // 0..126
    const int band = 31 - __clz(c + 1);        // chunks per band = 1<<band
    const int cidx = c + 1 - (1 << band);
    const int poff = 64 * (band + 1) + 512 * ((1 << band) - 1);
    const float* bp = bands + (size_t)sig * BAND_STRIDE + poff + cidx * 512;

    __shared__ __align__(16) __hip_bfloat16 xr[8][584]; // 8 shifted reversed copies
    __shared__ float segP[64 * 4];                      // band-6 wave partials

    for (int i = tid; i < 576; i += 256) {
        __hip_bfloat16 b = __float2bfloat16(bp[511 - i]);
        #pragma unroll
        for (int p = 0; p < 8; ++p) {
            int idx = i - p;
            if (idx >= 0) xr[p][idx] = b;
        }
    }
    __syncthreads();

    const int tl   = tid & 15;
    const int quad = (tid >> 4) & 3;
    const int wave = tid >> 6;

    bf16x8 bf0[4], bf1[4];
    #pragma unroll
    for (int ft = 0; ft < 4; ++ft) {
        const __hip_bfloat16* fp = filters + ((ft * 16 + tl) * 64 + quad * 8);
        bf0[ft] = *(const bf16x8*)(fp);
        bf1[ft] = *(const bf16x8*)(fp + 32);
    }

    int s0 = 511 - wave * 128 - tl + 8 * quad;
    const __hip_bfloat16* xp = &xr[0][0] + (s0 & 7) * 584 + (s0 & ~7);

    const int spc = 512 >> (2 + band);          // segs per chunk
    float* segO = segG + (size_t)(sig * NBANDS + band) * 64 * 128 + cidx * spc;

    const float NEG = -3.4e38f;
    float run0 = NEG, run1 = NEG, run2 = NEG, run3 = NEG;
    const int per = (band >= 2) ? (1 << (band - 2)) : 1;   // tiles per segment

    for (int it = 0; it < 8; ++it) {
        const int t0 = wave * 128 + it * 16;
        bf16x8 a0 = *(const bf16x8*)(xp);
        bf16x8 a1 = *(const bf16x8*)(xp + 32);
        xp -= 16;
        f32x4 ac0 = {0.f,0.f,0.f,0.f}, ac1 = ac0, ac2 = ac0, ac3 = ac0;
        ac0 = __builtin_amdgcn_mfma_f32_16x16x32_bf16(a0, bf0[0], ac0, 0, 0, 0);
        ac0 = __builtin_amdgcn_mfma_f32_16x16x32_bf16(a1, bf1[0], ac0, 0, 0, 0);
        ac1 = __builtin_amdgcn_mfma_f32_16x16x32_bf16(a0, bf0[1], ac1, 0, 0, 0);
        ac1 = __builtin_amdgcn_mfma_f32_16x16x32_bf16(a1, bf1[1], ac1, 0, 0, 0);
        ac2 = __builtin_amdgcn_mfma_f32_16x16x32_bf16(a0, bf0[2], ac2, 0, 0, 0);
        ac2 = __builtin_amdgcn_mfma_f32_16x16x32_bf16(a1, bf1[2], ac2, 0, 0, 0);
        ac3 = __builtin_amdgcn_mfma_f32_16x16x32_bf16(a0, bf0[3], ac3, 0, 0, 0);
        ac3 = __builtin_amdgcn_mfma_f32_16x16x32_bf16(a1, bf1[3], ac3, 0, 0, 0);
        float m0 = fmaxf(fmaxf(ac0[0], ac0[1]), fmaxf(ac0[2], ac0[3]));
        float m1 = fmaxf(fmaxf(ac1[0], ac1[1]), fmaxf(ac1[2], ac1[3]));
        float m2 = fmaxf(fmaxf(ac2[0], ac2[1]), fmaxf(ac2[2], ac2[3]));
        float m3 = fmaxf(fmaxf(ac3[0], ac3[1]), fmaxf(ac3[2], ac3[3]));
        if (band == 0) {
            int sb = (t0 >> 2) + quad;
            segO[(tl     ) * 128 + sb] = m0;
            segO[(tl + 16) * 128 + sb] = m1;
            segO[(tl + 32) * 128 + sb] = m2;
            segO[(tl + 48) * 128 + sb] = m3;
        } else if (band == 1) {
            m0 = fmaxf(m0, __shfl_xor(m0, 16));
            m1 = fmaxf(m1, __shfl_xor(m1, 16));
            m2 = fmaxf(m2, __shfl_xor(m2, 16));
            m3 = fmaxf(m3, __shfl_xor(m3, 16));
            if ((quad & 1) == 0) {
                int sb = (t0 >> 3) + (quad >> 1);
                segO[(tl     ) * 128 + sb] = m0;
                segO[(tl + 16) * 128 + sb] = m1;
                segO[(tl + 32) * 128 + sb] = m2;
                segO[(tl + 48) * 128 + sb] = m3;
            }
        } else {
            m0 = fmaxf(m0, __shfl_xor(m0, 16)); m0 = fmaxf(m0, __shfl_xor(m0, 32));
            m1 = fmaxf(m1, __shfl_xor(m1, 16)); m1 = fmaxf(m1, __shfl_xor(m1, 32));
            m2 = fmaxf(m2, __shfl_xor(m2, 16)); m2 = fmaxf(m2, __shfl_xor(m2, 32));
            m3 = fmaxf(m3, __shfl_xor(m3, 16)); m3 = fmaxf(m3, __shfl_xor(m3, 32));
            run0 = fmaxf(run0, m0); run1 = fmaxf(run1, m1);
            run2 = fmaxf(run2, m2); run3 = fmaxf(run3, m3);
            if (((it + 1) & (per - 1)) == 0) {
                int sb = t0 >> (2 + band);
                float rv = quad == 0 ? run0 : quad == 1 ? run1
                         : quad == 2 ? run2 : run3;
                segO[(tl + 16 * quad) * 128 + sb] = rv;
                run0 = NEG; run1 = NEG; run2 = NEG; run3 = NEG;
            }
        }
    }
    if (band == 6) {
        float rv = quad == 0 ? run0 : quad == 1 ? run1
                 : quad == 2 ? run2 : run3;
        segP[(tl + 16 * quad) * 4 + wave] = rv;
        __syncthreads();
        if (tid < 128) {
            int f = tid & 63, sg = tid >> 6;
            segO[f * 128 + sg] =
                fmaxf(segP[f * 4 + 2 * sg], segP[f * 4 + 2 * sg + 1]);
        }
    }
}

// ---------------------------------------------------------------------------
// K4: pool + top-128 via radix select + small bitonic sort (proven r9)
__global__ __launch_bounds__(256) void k_topk(
    const float* __restrict__ segG,
    float* __restrict__ topv, int* __restrict__ topi)
{
    const int tid = threadIdx.x;
    const int band = blockIdx.x, sig = blockIdx.y;
    const float* segB = segG + (size_t)(sig * NBANDS + band) * 64 * 128;

    __shared__ unsigned hist[256];
    __shared__ unsigned scan[256];
    __shared__ unsigned long long list[512];
    __shared__ int sh_B, sh_nA, sh_cnt, sh_num;

    unsigned long long kk[16];
    #pragma unroll
    for (int q = 0; q < 16; ++q) {
        int i = q * 256 + tid;
        int f = i >> 6, t = i & 63;
        const float* sg = segB + f * 128;
        float m = fmaxf(sg[2 * t], sg[2 * t + 1]);
        if (t > 0)  m = fmaxf(m, sg[2 * t - 1]);
        if (t < 63) m = fmaxf(m, sg[2 * t + 2]);
        kk[q] = ((unsigned long long)encf(m) << 32) | (unsigned)(4095 - i);
    }

    int shift = 56;
    unsigned long long prefix = 0;
    int nA = 0;
    for (int lev = 0; lev < 8; ++lev) {
        hist[tid] = 0;
        __syncthreads();
        #pragma unroll
        for (int q = 0; q < 16; ++q) {
            bool inpre = (lev == 0) || ((kk[q] >> (shift + 8)) == prefix);
            if (inpre) atomicAdd(&hist[(unsigned)((kk[q] >> shift) & 255u)], 1u);
        }
        __syncthreads();
        scan[tid] = hist[tid];
        __syncthreads();
        for (int off = 1; off < 256; off <<= 1) {
            unsigned v = scan[tid] + ((tid + off < 256) ? scan[tid + off] : 0u);
            __syncthreads();
            scan[tid] = v;
            __syncthreads();
        }
        {
            unsigned ge = (unsigned)nA + scan[tid];
            unsigned gt = (unsigned)nA + ((tid < 255) ? scan[tid + 1] : 0u);
            if (ge >= 128u && gt < 128u) {
                sh_B = tid; sh_nA = (int)gt; sh_cnt = (int)hist[tid];
            }
        }
        __syncthreads();
        prefix = (prefix << 8) | (unsigned)sh_B;
        nA = sh_nA;
        if (nA + sh_cnt <= 511 || shift == 0) break;
        shift -= 8;
        __syncthreads();
    }

    list[tid] = 0ull; list[tid + 256] = 0ull;
    if (tid == 0) sh_num = 0;
    __syncthreads();
    #pragma unroll
    for (int q = 0; q < 16; ++q) {
        if ((kk[q] >> shift) >= prefix) {
            int p = atomicAdd(&sh_num, 1);
            if (p < 512) list[p] = kk[q];
        }
    }
    __syncthreads();

    for (int k = 2; k <= 512; k <<= 1) {
        for (int j = k >> 1; j > 0; j >>= 1) {
            for (int w = tid; w < 512; w += 256) {
                int l = w ^ j;
                if (l > w) {
                    unsigned long long av = list[w], bv = list[l];
                    bool up = ((w & k) == 0);
                    if ((av > bv) == up) { list[w] = bv; list[l] = av; }
                }
            }
            __syncthreads();
        }
    }
    if (tid < K_TOP) {
        unsigned long long key = list[511 - tid];   // rank tid (descending)
        const size_t ob = ((size_t)sig * NBANDS + band) * K_TOP + tid;
        topv[ob] = decf((unsigned)(key >> 32));
        topi[ob] = 4095 - (int)(key & 0xFFFFFFFFu);
    }
}

// ---------------------------------------------------------------------------
// K5: loss partial sums (proven r4)
__global__ __launch_bounds__(256) void k_loss(
    const float* __restrict__ topv, const int* __restrict__ topi,
    const __hip_bfloat16* __restrict__ PT, const __hip_bfloat16* __restrict__ PF,
    float* __restrict__ accum)
{
    const int tid = threadIdx.x;
    const int band = blockIdx.x, b = blockIdx.y;
    const size_t bt = ((size_t)b * NBANDS + band) * K_TOP;
    const size_t br = ((size_t)(8 + b) * NBANDS + band) * K_TOP;
    float sum = 0.f;
    for (int k = 0; k < K_TOP; ++k) {
        float vt = topv[bt + k]; int it = topi[bt + k];
        float vr = topv[br + k]; int ir = topi[br + k];
        if (tid < 128) {
            float a = vt * bf2f(PT[(it & 63) * 128 + tid]);
            float c = vr * bf2f(PT[(ir & 63) * 128 + tid]);
            sum += fabsf(a - c);
        } else {
            int j = tid - 128;
            float a = bf2f(PF[(it >> 6) * 128 + j]);
            float c = bf2f(PF[(ir >> 6) * 128 + j]);
            sum += fabsf(a - c);
        }
    }
    __shared__ float red[256];
    red[tid] = sum;
    __syncthreads();
    for (int ofs = 128; ofs > 0; ofs >>= 1) {
        if (tid < ofs) red[tid] += red[tid + ofs];
        __syncthreads();
    }
    if (tid == 0) atomicAdd(accum, red[0]);
}

// ---------------------------------------------------------------------------
// K6: finalize + canary + dual-format store (proven r4)
__global__ __launch_bounds__(256) void k_final(
    const float* __restrict__ C, const float* __restrict__ bands,
    const float* __restrict__ segG, const float* __restrict__ topv,
    const float* __restrict__ accum, unsigned* __restrict__ out)
{
    const int tid = threadIdx.x;
    float s1 = 0.f, s2 = 0.f, s3 = 0.f, s4 = 0.f;
    for (int i = tid; i < 32768; i += 256) s1 += fabsf(C[i]);
    for (int i = tid; i < 512;   i += 256) s2 += fabsf(bands[64 + i]);
    for (int i = tid; i < 4096;  i += 256) s3 += fabsf(segG[i]);
    for (int i = tid; i < 128;   i += 256) s4 += fabsf(topv[i]);
    __shared__ float r1[256], r2[256], r3[256], r4[256];
    r1[tid] = s1; r2[tid] = s2; r3[tid] = s3; r4[tid] = s4;
    __syncthreads();
    for (int ofs = 128; ofs > 0; ofs >>= 1) {
        if (tid < ofs) {
            r1[tid] += r1[tid + ofs]; r2[tid] += r2[tid + ofs];
            r3[tid] += r3[tid + ofs]; r4[tid] += r4[tid + ofs];
        }
        __syncthreads();
    }
    if (tid == 0) {
        float L = accum[0] * (1.0f / 1835008.0f);
        unsigned lu = __float_as_uint(L);
        bool isnanL = ((lu & 0x7F800000u) == 0x7F800000u) && (lu & 0x007FFFFFu);
        float code;
        if      (r1[0] < 1e-3f)  code = 100.f;
        else if (r2[0] < 1e-6f)  code = 200.f;
        else if (r3[0] < 1e-6f)  code = 300.f;
        else if (r4[0] < 1e-9f)  code = 350.f;
        else if (isnanL)         code = 500.f;
        else if (L == 0.f)       code = 400.f;
        else if (fabsf(L) < 1e-6f) code = 600.f;
        else                     code = L;
        unsigned fb = __float_as_uint(code);
        unsigned hb = (fb + 0x7FFFu + ((fb >> 16) & 1u)) >> 16;
        out[0] = (hb << 16) | hb;
    }
}

// ---------------------------------------------------------------------------
extern "C" void kernel_launch(void* const* d_in, const int* in_sizes, int n_in,
                              void* d_out, int out_size, void* d_ws, size_t ws_size,
                              hipStream_t stream)
{
    float* C      = (float*)d_ws;                          // 524288 f
    float* bands  = C + (size_t)NSIG * NBINS * 2;          // 1047552 f
    float* segG   = bands + (size_t)NSIG * BAND_STRIDE;    // 917504 f
    float* topv   = segG + (size_t)NSIG * NBANDS * 64 * 128; // 14336 f
    int*   topi   = (int*)(topv + (size_t)NSIG * NBANDS * K_TOP);
    float* accum  = (float*)(topi + (size_t)NSIG * NBANDS * K_TOP);
    __hip_bfloat16* staged = (__hip_bfloat16*)(accum + 4);  // 16B-aligned
    float* TG = (float*)(staged + ST_TOT);   // T and G alias (T dead before G)
    float* T  = TG;
    float* G  = TG;

    const __hip_bfloat16* xstage = staged + ST_X;
    const __hip_bfloat16* fst    = staged + ST_F;
    const __hip_bfloat16* pts    = staged + ST_PT;
    const __hip_bfloat16* pfs    = staged + ST_PF;

    hipMemsetAsync(d_out, 0x3F, 4, stream);   // no-kernel sentinel

    k_stage  <<<dim3((ST_TOT + 255) / 256 + 1), 256, 0, stream>>>(
                 d_in[0], d_in[1], d_in[2], d_in[3], d_in[4],
                 staged, bands, accum);
    k_fwd1   <<<dim3(16, NSIG),       256, 0, stream>>>(xstage, T);
    k_fwd2   <<<dim3(128, NSIG),      128, 0, stream>>>(T, C);
    k_synthA <<<dim3(64, NSIG),       256, 0, stream>>>(C, G);
    k_synthB <<<dim3(64, NSIG),       256, 0, stream>>>(C, G, bands);
    k_conv   <<<dim3(127, NSIG),      256, 0, stream>>>(bands, fst, segG);
    k_topk   <<<dim3(NBANDS, NSIG),   256, 0, stream>>>(segG, topv, topi);
    k_loss   <<<dim3(NBANDS, 8),      256, 0, stream>>>(topv, topi, pts, pfs, accum);
    k_final  <<<1, 256, 0, stream>>>(C, bands, segG, topv, accum,
                                     (unsigned*)d_out);
}